// Round 10
// baseline (194.034 us; speedup 1.0000x reference)
//
#include <hip/hip_runtime.h>

// VQ-VAE vector quantizer: B=32,C=64,H=64,W=64, K=512, DECAY=0.99, EPS=1e-5
// N = 131072 vectors, dim 64.
// R10: 3-launch pipeline. (1) vq_argmin: fused prep (cb->LDS hi/lo bf16 split,
// esq in-block), 1024 thr / 4 waves per SIMD, R9-proven MFMA K-loop + top-2 +
// in-kernel exact-fp32 refine -> final bkg; also zeroes hsum/acc_loss.
// (2) vq_fused: blocks 0-255 = out/loss/hist (R9 vq_out body), 256-511 =
// onehot-GEMM segsum (R9-proven). (3) vq_final: scalars + codebook merged
// (per-block smoothed recompute from hsum).

typedef __attribute__((ext_vector_type(8))) short bf16x8;
typedef __attribute__((ext_vector_type(16))) float f32x16;

#define MFMA32 __builtin_amdgcn_mfma_f32_32x32x16_bf16

__device__ __forceinline__ unsigned short f2bf(float f) {
    unsigned u = __float_as_uint(f);
    return (unsigned short)((u + 0x7fffu + ((u >> 16) & 1u)) >> 16);
}
__device__ __forceinline__ float bf2f(unsigned short h) {
    return __uint_as_float(((unsigned)h) << 16);
}

// top-2 update; kq ascending -> strict < keeps first (numpy argmin semantics)
__device__ __forceinline__ void upd(float s, int kq, float& b1, int& q1, float& b2, int& q2) {
    bool t1 = s < b1;
    bool t2 = s < b2;
    float nb2 = t1 ? b1 : (t2 ? s : b2);
    int   nq2 = t1 ? q1 : (t2 ? kq : q2);
    b2 = nb2; q2 = nq2;
    b1 = t1 ? s : b1;
    q1 = t1 ? kq : q1;
}

// exact fp32 re-decision between k1,k2 (R2/R9-proven ordering)
__device__ __forceinline__ int refine_pair(int k1, int k2, long gx,
        const float* __restrict__ x, const float* __restrict__ cbg,
        const float* esq) {
    const float4* e1 = (const float4*)(cbg + (k1 << 6));
    const float4* e2 = (const float4*)(cbg + (k2 << 6));
    float a0 = 0.f, a1 = 0.f, c0 = 0.f, c1 = 0.f;
    #pragma unroll 4
    for (int j = 0; j < 16; ++j) {
        float4 ea = e1[j], eb = e2[j];
        float x0 = x[gx + (long)(4 * j + 0) * 4096];
        float x1 = x[gx + (long)(4 * j + 1) * 4096];
        float x2 = x[gx + (long)(4 * j + 2) * 4096];
        float x3 = x[gx + (long)(4 * j + 3) * 4096];
        a0 = fmaf(x0, ea.x, a0); a1 = fmaf(x1, ea.y, a1);
        a0 = fmaf(x2, ea.z, a0); a1 = fmaf(x3, ea.w, a1);
        c0 = fmaf(x0, eb.x, c0); c1 = fmaf(x1, eb.y, c1);
        c0 = fmaf(x2, eb.z, c0); c1 = fmaf(x3, eb.w, c1);
    }
    float s1 = esq[k1] - 2.f * (a0 + a1);
    float s2 = esq[k2] - 2.f * (c0 + c1);
    return (s2 < s1 || (s2 == s1 && k2 < k1)) ? k2 : k1;
}

// LDS: cbhi 16384 fl | cblo 16384 fl | esq 512 fl = 133,120 B; 1024 thr -> 4 waves/SIMD
#define AM_LDS_FLOATS 33280

__global__ void __launch_bounds__(1024)
vq_argmin(const float* __restrict__ x, const float* __restrict__ cbg,
          unsigned short* __restrict__ bkg, float* __restrict__ zero528) {
    extern __shared__ float lds[];
    float* esq = lds + 32768;
    bf16x8* chi = (bf16x8*)lds;
    bf16x8* clo = (bf16x8*)(lds + 16384);
    const int tid  = threadIdx.x;
    const int lane = tid & 63;
    const int wv   = tid >> 6;     // 0..15
    const int l31  = lane & 31;
    const int hh   = lane >> 5;

    // ---- fused prep: thread t < 512 converts codebook row t (c ascending:
    //      cbase(u)=8u, so esq fmaf order == proven prep order) ----
    if (tid < 512) {
        const float4* rowp = (const float4*)(cbg + (tid << 6));
        float s = 0.f;
        #pragma unroll
        for (int u = 0; u < 8; ++u) {
            float4 va = rowp[u * 2], vb = rowp[u * 2 + 1];
            const float v[8] = {va.x, va.y, va.z, va.w, vb.x, vb.y, vb.z, vb.w};
            bf16x8 h8, l8;
            #pragma unroll
            for (int j = 0; j < 8; ++j) {
                float e = v[j];
                s = fmaf(e, e, s);
                unsigned short hb = f2bf(e);
                float lo = e - bf2f(hb);
                h8[j] = (short)hb;
                l8[j] = (short)f2bf(lo);
            }
            chi[u * 512 + tid] = h8;
            clo[u * 512 + tid] = l8;
        }
        esq[tid] = s;
    }
    // zero hsum(512)+acc_loss(16): all blocks write 0 -- race-safe, done before consumers
    if (tid < 528) zero528[tid] = 0.f;

    // ---- B build: 2 n-tiles per wave (-2x, hi/lo via cvt_pk; R9-proven) ----
    const int nb = blockIdx.x * 1024 + wv * 64;
    bf16x8 B0h[4], B0l[4], B1h[4], B1l[4];
    #pragma unroll
    for (int ct = 0; ct < 2; ++ct) {
        const int n = nb + ct * 32 + l31;
        const long gx = (long)(n >> 12) * 262144 + (long)((n >> 6) & 63) * 64 + (n & 63);
        #pragma unroll
        for (int cs = 0; cs < 4; ++cs) {
            float v[8];
            #pragma unroll
            for (int j = 0; j < 8; ++j)
                v[j] = -2.f * x[gx + (long)(cs * 16 + hh * 8 + j) * 4096];
            union { unsigned u[4]; bf16x8 v8; } uh, ul;
            #pragma unroll
            for (int p = 0; p < 4; ++p) {
                unsigned hp, lp;
                asm("v_cvt_pk_bf16_f32 %0, %1, %2" : "=v"(hp) : "v"(v[2*p]), "v"(v[2*p+1]));
                float r0 = v[2*p]     - __uint_as_float(hp << 16);
                float r1 = v[2*p + 1] - __uint_as_float(hp & 0xFFFF0000u);
                asm("v_cvt_pk_bf16_f32 %0, %1, %2" : "=v"(lp) : "v"(r0), "v"(r1));
                uh.u[p] = hp; ul.u[p] = lp;
            }
            if (ct == 0) { B0h[cs] = uh.v8; B0l[cs] = ul.v8; }
            else         { B1h[cs] = uh.v8; B1l[cs] = ul.v8; }
        }
    }
    __syncthreads();

    // ---- K loop: 16 tiles x 32 codes, 2-deep A ping-pong, esq in acc-init ----
    float b1a = 3.4e38f, b2a = 3.4e38f, b1b = 3.4e38f, b2b = 3.4e38f;
    int   q1a = 0, q2a = 0, q1b = 0, q2b = 0;
    bf16x8 Xh[4], Xl[4], Yh[4], Yl[4];

#define LOADA(Ah, Al, kt) { _Pragma("unroll") for (int cs = 0; cs < 4; ++cs) { \
        const int fi = (cs * 2 + hh) * 512 + (kt) * 32 + l31; \
        Ah[cs] = chi[fi]; Al[cs] = clo[fi]; } }

#define STEP(Ah, Al, kt) { \
        f32x16 acc0, acc1; \
        _Pragma("unroll") for (int g = 0; g < 4; ++g) { \
            float4 e4 = *(const float4*)(esq + (kt) * 32 + 8 * g + 4 * hh); \
            acc0[4*g] = e4.x; acc0[4*g+1] = e4.y; acc0[4*g+2] = e4.z; acc0[4*g+3] = e4.w; \
            acc1[4*g] = e4.x; acc1[4*g+1] = e4.y; acc1[4*g+2] = e4.z; acc1[4*g+3] = e4.w; } \
        _Pragma("unroll") for (int cs = 0; cs < 4; ++cs) { \
            acc0 = MFMA32(Ah[cs], B0h[cs], acc0, 0, 0, 0); \
            acc1 = MFMA32(Ah[cs], B1h[cs], acc1, 0, 0, 0); \
            acc0 = MFMA32(Al[cs], B0h[cs], acc0, 0, 0, 0); \
            acc1 = MFMA32(Al[cs], B1h[cs], acc1, 0, 0, 0); \
            acc0 = MFMA32(Ah[cs], B0l[cs], acc0, 0, 0, 0); \
            acc1 = MFMA32(Ah[cs], B1l[cs], acc1, 0, 0, 0); } \
        _Pragma("unroll") for (int e = 0; e < 16; ++e) { \
            int kq = (kt) * 32 + (e & 3) + 8 * (e >> 2); \
            upd(acc0[e], kq, b1a, q1a, b2a, q2a); \
            upd(acc1[e], kq, b1b, q1b, b2b, q2b); } }

    LOADA(Xh, Xl, 0)
    #pragma unroll 1
    for (int ktp = 0; ktp < 16; ktp += 2) {
        LOADA(Yh, Yl, ktp + 1)
        STEP(Xh, Xl, ktp)
        if (ktp + 2 < 16) LOADA(Xh, Xl, ktp + 2)
        STEP(Yh, Yl, ktp + 1)
    }

    // ---- merge hh halves (true k = kq + 4*hh) + in-kernel refine + final bkg ----
#define MERGE(b1, q1, b2, q2, ct) { \
        float mb1 = b1, mb2 = b2; int mk1 = q1 + 4 * hh, mk2 = q2 + 4 * hh; \
        float ob1 = __shfl_xor(mb1, 32, 64); int ok1 = __shfl_xor(mk1, 32, 64); \
        float ob2 = __shfl_xor(mb2, 32, 64); int ok2 = __shfl_xor(mk2, 32, 64); \
        bool t = (ob1 < mb1) || (ob1 == mb1 && ok1 < mk1); \
        float w1 = t ? ob1 : mb1;  int wk1 = t ? ok1 : mk1; \
        float l1 = t ? mb1 : ob1;  int lk1 = t ? mk1 : ok1; \
        float w2c = t ? ob2 : mb2; int wk2c = t ? ok2 : mk2; \
        bool t2 = (w2c < l1) || (w2c == l1 && wk2c < lk1); \
        float w2 = t2 ? w2c : l1;  int wk2 = t2 ? wk2c : lk1; \
        if (hh == 0) { \
            int kk = wk1; \
            if (wk2 != wk1 && (w2 - w1 < 2e-3f)) { \
                const int n = nb + (ct) * 32 + l31; \
                const long gx = (long)(n >> 12) * 262144 \
                              + (long)((n >> 6) & 63) * 64 + (n & 63); \
                kk = refine_pair(wk1, wk2, gx, x, cbg, esq); \
            } \
            bkg[nb + (ct) * 32 + l31] = (unsigned short)kk; } }

    MERGE(b1a, q1a, b2a, q2a, 0)
    MERGE(b1b, q1b, b2b, q2b, 1)
#undef LOADA
#undef STEP
#undef MERGE
}

// ---- fused consumers of bkg: blocks 0-255 out/loss/hist, 256-511 segsum GEMM ----
__global__ void __launch_bounds__(512)
vq_fused(const float* __restrict__ x, const float* __restrict__ cbg,
         const unsigned short* __restrict__ bkg, float* __restrict__ out,
         float* __restrict__ hsum, float* __restrict__ acc_loss,
         float* __restrict__ slabs) {
    __shared__ float hist[512];
    __shared__ float lred[8];
    const int tid = threadIdx.x;
    if (blockIdx.x < 256) {
        // ---- out (= q, == x+(q-x) to 1 ulp, R5-proven) + loss + counts ----
        hist[tid] = 0.f;
        __syncthreads();
        const int n  = blockIdx.x * 512 + tid;
        const long gx = (long)(n >> 12) * 262144 + (long)((n >> 6) & 63) * 64 + (n & 63);
        const int k1 = bkg[n];
        atomicAdd(&hist[k1], 1.0f);
        const float4* q4 = (const float4*)(cbg + (k1 << 6));
        float lsum = 0.f;
        #pragma unroll
        for (int j = 0; j < 16; ++j) {
            float4 q = q4[j];
            const float qv[4] = {q.x, q.y, q.z, q.w};
            #pragma unroll
            for (int r = 0; r < 4; ++r) {
                const int c = 4 * j + r;
                float xc = x[gx + (long)c * 4096];
                out[gx + (long)c * 4096] = qv[r];
                float d = xc - qv[r];
                lsum = fmaf(d, d, lsum);
            }
        }
        #pragma unroll
        for (int o = 32; o > 0; o >>= 1) lsum += __shfl_down(lsum, o, 64);
        if ((tid & 63) == 0) lred[tid >> 6] = lsum;
        __syncthreads();
        if (tid == 0) {
            float l = ((lred[0] + lred[1]) + (lred[2] + lred[3]))
                    + ((lred[4] + lred[5]) + (lred[6] + lred[7]));
            atomicAdd(acc_loss, l);
        }
        { float v = hist[tid]; if (v != 0.f) atomicAdd(&hsum[tid], v); }
    } else {
        // ---- segment sum as onehot MFMA GEMM (R9-proven, zero atomics) ----
        const int lane = tid & 63;
        const int w    = tid >> 6;
        const int l31  = lane & 31;
        const int hh   = lane >> 5;
        const int bix  = blockIdx.x - 256;
        const int n0   = bix * 512;
        const float* xpl = x + (long)(n0 >> 12) * 262144 + (n0 & 4095);
        const int t0 = w * 32 + l31;
        const int t1 = (w + 8) * 32 + l31;
        f32x16 aA0 = {}, aA1 = {}, aB0 = {}, aB1 = {};

        #pragma unroll 1
        for (int b16 = 0; b16 < 32; ++b16) {
            const int nofs = b16 * 16 + hh * 8;
            bf16x8 Bf0, Bf1;
            const float* p0 = xpl + (long)l31 * 4096 + nofs;
            const float* p1 = xpl + (long)(32 + l31) * 4096 + nofs;
            #pragma unroll
            for (int j = 0; j < 8; ++j) {
                Bf0[j] = (short)f2bf(p0[j]);
                Bf1[j] = (short)f2bf(p1[j]);
            }
            bf16x8 A0, A1;
            const unsigned short* kp = bkg + n0 + nofs;
            #pragma unroll
            for (int j = 0; j < 8; ++j) {
                const int k = kp[j];
                A0[j] = (k == t0) ? (short)0x3F80 : (short)0;
                A1[j] = (k == t1) ? (short)0x3F80 : (short)0;
            }
            aA0 = MFMA32(A0, Bf0, aA0, 0, 0, 0);
            aA1 = MFMA32(A0, Bf1, aA1, 0, 0, 0);
            aB0 = MFMA32(A1, Bf0, aB0, 0, 0, 0);
            aB1 = MFMA32(A1, Bf1, aB1, 0, 0, 0);
        }
        float* slab = slabs + (long)bix * 32768;
        #pragma unroll
        for (int e = 0; e < 16; ++e) {
            const int row = (e & 3) + 8 * (e >> 2) + 4 * hh;
            slab[(w * 32 + row) * 64 + l31]            = aA0[e];
            slab[(w * 32 + row) * 64 + 32 + l31]       = aA1[e];
            slab[((w + 8) * 32 + row) * 64 + l31]      = aB0[e];
            slab[((w + 8) * 32 + row) * 64 + 32 + l31] = aB1[e];
        }
    }
}

// ---- final: scalars (block 0) + codebook; smoothed recomputed per block ----
__global__ void __launch_bounds__(512)
vq_final(const float* __restrict__ slabs, const float* __restrict__ hsum,
         const float* __restrict__ acc_loss, const float* __restrict__ ema_cs,
         const float* __restrict__ ema_w, float* __restrict__ out_scalars,
         float* __restrict__ out_cb) {
    __shared__ float sm[512];
    __shared__ float s_red[17];
    const int tid = threadIdx.x;           // tid == code k
    float cnt = hsum[tid];
    float ncs = 0.99f * ema_cs[tid] + 0.01f * cnt;
    float v1 = ncs;
    float v2 = (cnt > 0.f) ? 1.f : 0.f;
    #pragma unroll
    for (int o = 32; o > 0; o >>= 1) {
        v1 += __shfl_down(v1, o, 64);
        v2 += __shfl_down(v2, o, 64);
    }
    const int wv = tid >> 6;
    if ((tid & 63) == 0) { s_red[wv] = v1; s_red[wv + 8] = v2; }
    __syncthreads();
    if (tid == 0) {
        float nn = 0.f, uq = 0.f;
        #pragma unroll
        for (int i = 0; i < 8; ++i) { nn += s_red[i]; uq += s_red[i + 8]; }
        s_red[16] = nn;
        if (blockIdx.x == 0) {
            out_scalars[0] = acc_loss[0] / 8388608.f;
            out_scalars[1] = uq;
        }
    }
    __syncthreads();
    float nn = s_red[16];
    sm[tid] = (ncs + 1e-5f) / (nn + 512.f * 1e-5f) * nn;
    __syncthreads();
    const int e = blockIdx.x * 512 + tid;  // e = k*64 + c
    float s = 0.f;
    #pragma unroll 8
    for (int b = 0; b < 256; ++b) s += slabs[(long)b * 32768 + e];
    float nw = 0.99f * ema_w[e] + 0.01f * s;
    out_cb[e] = nw / sm[e >> 6];
}

extern "C" void kernel_launch(void* const* d_in, const int* in_sizes, int n_in,
                              void* d_out, int out_size, void* d_ws, size_t ws_size,
                              hipStream_t stream) {
    const float* x      = (const float*)d_in[0];
    const float* cb     = (const float*)d_in[1];
    const float* ema_cs = (const float*)d_in[2];
    const float* ema_w  = (const float*)d_in[3];

    float* out     = (float*)d_out;
    float* scalars = out + 8388608;
    float* out_cb  = out + 8388610;
    float* ws      = (float*)d_ws;

    // ws layout (floats):
    float* slabs    = ws;                               // 256*32768 = 8,388,608 (32MB)
    float* hsum     = slabs + 8388608;                  // 512 (+16 acc_loss, contiguous)
    float* acc_loss = hsum + 512;                       // 16
    unsigned short* bkg = (unsigned short*)(acc_loss + 16);  // 131072 u16
    // total ~33.8 MB (R4 proved >= 34.6 MB available)

    vq_argmin<<<128, 1024, AM_LDS_FLOATS * sizeof(float), stream>>>(x, cb, bkg, hsum);
    vq_fused<<<512, 512, 0, stream>>>(x, cb, bkg, out, hsum, acc_loss, slabs);
    vq_final<<<64, 512, 0, stream>>>(slabs, hsum, acc_loss, ema_cs, ema_w, scalars, out_cb);
}

// Round 11
// 193.618 us; speedup vs baseline: 1.0022x; 1.0022x over previous
//
#include <hip/hip_runtime.h>

// VQ-VAE vector quantizer: B=32,C=64,H=64,W=64, K=512, DECAY=0.99, EPS=1e-5
// N = 131072 vectors, dim 64.
// R11 = R10 with the spill fix: vq_argmin __launch_bounds__(1024, 4) -> 128-VGPR
// cap (R9 body needs ~100). R10's bare (1024) made the allocator target 64 VGPR
// (8 waves/SIMD heuristic; dynamic LDS hides the 1-block/CU limit) -> 94 MB of
// scratch spill per dispatch, 143 us. Everything else identical to R10.

typedef __attribute__((ext_vector_type(8))) short bf16x8;
typedef __attribute__((ext_vector_type(16))) float f32x16;

#define MFMA32 __builtin_amdgcn_mfma_f32_32x32x16_bf16

__device__ __forceinline__ unsigned short f2bf(float f) {
    unsigned u = __float_as_uint(f);
    return (unsigned short)((u + 0x7fffu + ((u >> 16) & 1u)) >> 16);
}
__device__ __forceinline__ float bf2f(unsigned short h) {
    return __uint_as_float(((unsigned)h) << 16);
}

// top-2 update; kq ascending -> strict < keeps first (numpy argmin semantics)
__device__ __forceinline__ void upd(float s, int kq, float& b1, int& q1, float& b2, int& q2) {
    bool t1 = s < b1;
    bool t2 = s < b2;
    float nb2 = t1 ? b1 : (t2 ? s : b2);
    int   nq2 = t1 ? q1 : (t2 ? kq : q2);
    b2 = nb2; q2 = nq2;
    b1 = t1 ? s : b1;
    q1 = t1 ? kq : q1;
}

// exact fp32 re-decision between k1,k2 (R2/R9-proven ordering)
__device__ __forceinline__ int refine_pair(int k1, int k2, long gx,
        const float* __restrict__ x, const float* __restrict__ cbg,
        const float* esq) {
    const float4* e1 = (const float4*)(cbg + (k1 << 6));
    const float4* e2 = (const float4*)(cbg + (k2 << 6));
    float a0 = 0.f, a1 = 0.f, c0 = 0.f, c1 = 0.f;
    #pragma unroll 4
    for (int j = 0; j < 16; ++j) {
        float4 ea = e1[j], eb = e2[j];
        float x0 = x[gx + (long)(4 * j + 0) * 4096];
        float x1 = x[gx + (long)(4 * j + 1) * 4096];
        float x2 = x[gx + (long)(4 * j + 2) * 4096];
        float x3 = x[gx + (long)(4 * j + 3) * 4096];
        a0 = fmaf(x0, ea.x, a0); a1 = fmaf(x1, ea.y, a1);
        a0 = fmaf(x2, ea.z, a0); a1 = fmaf(x3, ea.w, a1);
        c0 = fmaf(x0, eb.x, c0); c1 = fmaf(x1, eb.y, c1);
        c0 = fmaf(x2, eb.z, c0); c1 = fmaf(x3, eb.w, c1);
    }
    float s1 = esq[k1] - 2.f * (a0 + a1);
    float s2 = esq[k2] - 2.f * (c0 + c1);
    return (s2 < s1 || (s2 == s1 && k2 < k1)) ? k2 : k1;
}

// LDS: cbhi 16384 fl | cblo 16384 fl | esq 512 fl = 133,120 B; 1024 thr, 1 block/CU
#define AM_LDS_FLOATS 33280

__global__ void __launch_bounds__(1024, 4)
vq_argmin(const float* __restrict__ x, const float* __restrict__ cbg,
          unsigned short* __restrict__ bkg, float* __restrict__ zero528) {
    extern __shared__ float lds[];
    float* esq = lds + 32768;
    bf16x8* chi = (bf16x8*)lds;
    bf16x8* clo = (bf16x8*)(lds + 16384);
    const int tid  = threadIdx.x;
    const int lane = tid & 63;
    const int wv   = tid >> 6;     // 0..15
    const int l31  = lane & 31;
    const int hh   = lane >> 5;

    // ---- fused prep: thread t < 512 converts codebook row t (c ascending:
    //      esq fmaf order == proven prep order) ----
    if (tid < 512) {
        const float4* rowp = (const float4*)(cbg + (tid << 6));
        float s = 0.f;
        #pragma unroll
        for (int u = 0; u < 8; ++u) {
            float4 va = rowp[u * 2], vb = rowp[u * 2 + 1];
            const float v[8] = {va.x, va.y, va.z, va.w, vb.x, vb.y, vb.z, vb.w};
            bf16x8 h8, l8;
            #pragma unroll
            for (int j = 0; j < 8; ++j) {
                float e = v[j];
                s = fmaf(e, e, s);
                unsigned short hb = f2bf(e);
                float lo = e - bf2f(hb);
                h8[j] = (short)hb;
                l8[j] = (short)f2bf(lo);
            }
            chi[u * 512 + tid] = h8;
            clo[u * 512 + tid] = l8;
        }
        esq[tid] = s;
    }
    // zero hsum(512)+acc_loss(16): all blocks write 0 -- race-safe, done before consumers
    if (tid < 528) zero528[tid] = 0.f;

    // ---- B build: 2 n-tiles per wave (-2x, hi/lo via cvt_pk; R9-proven) ----
    const int nb = blockIdx.x * 1024 + wv * 64;
    bf16x8 B0h[4], B0l[4], B1h[4], B1l[4];
    #pragma unroll
    for (int ct = 0; ct < 2; ++ct) {
        const int n = nb + ct * 32 + l31;
        const long gx = (long)(n >> 12) * 262144 + (long)((n >> 6) & 63) * 64 + (n & 63);
        #pragma unroll
        for (int cs = 0; cs < 4; ++cs) {
            float v[8];
            #pragma unroll
            for (int j = 0; j < 8; ++j)
                v[j] = -2.f * x[gx + (long)(cs * 16 + hh * 8 + j) * 4096];
            union { unsigned u[4]; bf16x8 v8; } uh, ul;
            #pragma unroll
            for (int p = 0; p < 4; ++p) {
                unsigned hp, lp;
                asm("v_cvt_pk_bf16_f32 %0, %1, %2" : "=v"(hp) : "v"(v[2*p]), "v"(v[2*p+1]));
                float r0 = v[2*p]     - __uint_as_float(hp << 16);
                float r1 = v[2*p + 1] - __uint_as_float(hp & 0xFFFF0000u);
                asm("v_cvt_pk_bf16_f32 %0, %1, %2" : "=v"(lp) : "v"(r0), "v"(r1));
                uh.u[p] = hp; ul.u[p] = lp;
            }
            if (ct == 0) { B0h[cs] = uh.v8; B0l[cs] = ul.v8; }
            else         { B1h[cs] = uh.v8; B1l[cs] = ul.v8; }
        }
    }
    __syncthreads();

    // ---- K loop: 16 tiles x 32 codes, 2-deep A ping-pong, esq in acc-init ----
    float b1a = 3.4e38f, b2a = 3.4e38f, b1b = 3.4e38f, b2b = 3.4e38f;
    int   q1a = 0, q2a = 0, q1b = 0, q2b = 0;
    bf16x8 Xh[4], Xl[4], Yh[4], Yl[4];

#define LOADA(Ah, Al, kt) { _Pragma("unroll") for (int cs = 0; cs < 4; ++cs) { \
        const int fi = (cs * 2 + hh) * 512 + (kt) * 32 + l31; \
        Ah[cs] = chi[fi]; Al[cs] = clo[fi]; } }

#define STEP(Ah, Al, kt) { \
        f32x16 acc0, acc1; \
        _Pragma("unroll") for (int g = 0; g < 4; ++g) { \
            float4 e4 = *(const float4*)(esq + (kt) * 32 + 8 * g + 4 * hh); \
            acc0[4*g] = e4.x; acc0[4*g+1] = e4.y; acc0[4*g+2] = e4.z; acc0[4*g+3] = e4.w; \
            acc1[4*g] = e4.x; acc1[4*g+1] = e4.y; acc1[4*g+2] = e4.z; acc1[4*g+3] = e4.w; } \
        _Pragma("unroll") for (int cs = 0; cs < 4; ++cs) { \
            acc0 = MFMA32(Ah[cs], B0h[cs], acc0, 0, 0, 0); \
            acc1 = MFMA32(Ah[cs], B1h[cs], acc1, 0, 0, 0); \
            acc0 = MFMA32(Al[cs], B0h[cs], acc0, 0, 0, 0); \
            acc1 = MFMA32(Al[cs], B1h[cs], acc1, 0, 0, 0); \
            acc0 = MFMA32(Ah[cs], B0l[cs], acc0, 0, 0, 0); \
            acc1 = MFMA32(Ah[cs], B1l[cs], acc1, 0, 0, 0); } \
        _Pragma("unroll") for (int e = 0; e < 16; ++e) { \
            int kq = (kt) * 32 + (e & 3) + 8 * (e >> 2); \
            upd(acc0[e], kq, b1a, q1a, b2a, q2a); \
            upd(acc1[e], kq, b1b, q1b, b2b, q2b); } }

    LOADA(Xh, Xl, 0)
    #pragma unroll 1
    for (int ktp = 0; ktp < 16; ktp += 2) {
        LOADA(Yh, Yl, ktp + 1)
        STEP(Xh, Xl, ktp)
        if (ktp + 2 < 16) LOADA(Xh, Xl, ktp + 2)
        STEP(Yh, Yl, ktp + 1)
    }

    // ---- merge hh halves (true k = kq + 4*hh) + in-kernel refine + final bkg ----
#define MERGE(b1, q1, b2, q2, ct) { \
        float mb1 = b1, mb2 = b2; int mk1 = q1 + 4 * hh, mk2 = q2 + 4 * hh; \
        float ob1 = __shfl_xor(mb1, 32, 64); int ok1 = __shfl_xor(mk1, 32, 64); \
        float ob2 = __shfl_xor(mb2, 32, 64); int ok2 = __shfl_xor(mk2, 32, 64); \
        bool t = (ob1 < mb1) || (ob1 == mb1 && ok1 < mk1); \
        float w1 = t ? ob1 : mb1;  int wk1 = t ? ok1 : mk1; \
        float l1 = t ? mb1 : ob1;  int lk1 = t ? mk1 : ok1; \
        float w2c = t ? ob2 : mb2; int wk2c = t ? ok2 : mk2; \
        bool t2 = (w2c < l1) || (w2c == l1 && wk2c < lk1); \
        float w2 = t2 ? w2c : l1;  int wk2 = t2 ? wk2c : lk1; \
        if (hh == 0) { \
            int kk = wk1; \
            if (wk2 != wk1 && (w2 - w1 < 2e-3f)) { \
                const int n = nb + (ct) * 32 + l31; \
                const long gx = (long)(n >> 12) * 262144 \
                              + (long)((n >> 6) & 63) * 64 + (n & 63); \
                kk = refine_pair(wk1, wk2, gx, x, cbg, esq); \
            } \
            bkg[nb + (ct) * 32 + l31] = (unsigned short)kk; } }

    MERGE(b1a, q1a, b2a, q2a, 0)
    MERGE(b1b, q1b, b2b, q2b, 1)
#undef LOADA
#undef STEP
#undef MERGE
}

// ---- fused consumers of bkg: blocks 0-255 out/loss/hist, 256-511 segsum GEMM ----
__global__ void __launch_bounds__(512)
vq_fused(const float* __restrict__ x, const float* __restrict__ cbg,
         const unsigned short* __restrict__ bkg, float* __restrict__ out,
         float* __restrict__ hsum, float* __restrict__ acc_loss,
         float* __restrict__ slabs) {
    __shared__ float hist[512];
    __shared__ float lred[8];
    const int tid = threadIdx.x;
    if (blockIdx.x < 256) {
        // ---- out (= q, == x+(q-x) to 1 ulp, R5-proven) + loss + counts ----
        hist[tid] = 0.f;
        __syncthreads();
        const int n  = blockIdx.x * 512 + tid;
        const long gx = (long)(n >> 12) * 262144 + (long)((n >> 6) & 63) * 64 + (n & 63);
        const int k1 = bkg[n];
        atomicAdd(&hist[k1], 1.0f);
        const float4* q4 = (const float4*)(cbg + (k1 << 6));
        float lsum = 0.f;
        #pragma unroll
        for (int j = 0; j < 16; ++j) {
            float4 q = q4[j];
            const float qv[4] = {q.x, q.y, q.z, q.w};
            #pragma unroll
            for (int r = 0; r < 4; ++r) {
                const int c = 4 * j + r;
                float xc = x[gx + (long)c * 4096];
                out[gx + (long)c * 4096] = qv[r];
                float d = xc - qv[r];
                lsum = fmaf(d, d, lsum);
            }
        }
        #pragma unroll
        for (int o = 32; o > 0; o >>= 1) lsum += __shfl_down(lsum, o, 64);
        if ((tid & 63) == 0) lred[tid >> 6] = lsum;
        __syncthreads();
        if (tid == 0) {
            float l = ((lred[0] + lred[1]) + (lred[2] + lred[3]))
                    + ((lred[4] + lred[5]) + (lred[6] + lred[7]));
            atomicAdd(acc_loss, l);
        }
        { float v = hist[tid]; if (v != 0.f) atomicAdd(&hsum[tid], v); }
    } else {
        // ---- segment sum as onehot MFMA GEMM (R9-proven, zero atomics) ----
        const int lane = tid & 63;
        const int w    = tid >> 6;
        const int l31  = lane & 31;
        const int hh   = lane >> 5;
        const int bix  = blockIdx.x - 256;
        const int n0   = bix * 512;
        const float* xpl = x + (long)(n0 >> 12) * 262144 + (n0 & 4095);
        const int t0 = w * 32 + l31;
        const int t1 = (w + 8) * 32 + l31;
        f32x16 aA0 = {}, aA1 = {}, aB0 = {}, aB1 = {};

        #pragma unroll 1
        for (int b16 = 0; b16 < 32; ++b16) {
            const int nofs = b16 * 16 + hh * 8;
            bf16x8 Bf0, Bf1;
            const float* p0 = xpl + (long)l31 * 4096 + nofs;
            const float* p1 = xpl + (long)(32 + l31) * 4096 + nofs;
            #pragma unroll
            for (int j = 0; j < 8; ++j) {
                Bf0[j] = (short)f2bf(p0[j]);
                Bf1[j] = (short)f2bf(p1[j]);
            }
            bf16x8 A0, A1;
            const unsigned short* kp = bkg + n0 + nofs;
            #pragma unroll
            for (int j = 0; j < 8; ++j) {
                const int k = kp[j];
                A0[j] = (k == t0) ? (short)0x3F80 : (short)0;
                A1[j] = (k == t1) ? (short)0x3F80 : (short)0;
            }
            aA0 = MFMA32(A0, Bf0, aA0, 0, 0, 0);
            aA1 = MFMA32(A0, Bf1, aA1, 0, 0, 0);
            aB0 = MFMA32(A1, Bf0, aB0, 0, 0, 0);
            aB1 = MFMA32(A1, Bf1, aB1, 0, 0, 0);
        }
        float* slab = slabs + (long)bix * 32768;
        #pragma unroll
        for (int e = 0; e < 16; ++e) {
            const int row = (e & 3) + 8 * (e >> 2) + 4 * hh;
            slab[(w * 32 + row) * 64 + l31]            = aA0[e];
            slab[(w * 32 + row) * 64 + 32 + l31]       = aA1[e];
            slab[((w + 8) * 32 + row) * 64 + l31]      = aB0[e];
            slab[((w + 8) * 32 + row) * 64 + 32 + l31] = aB1[e];
        }
    }
}

// ---- final: scalars (block 0) + codebook; smoothed recomputed per block ----
__global__ void __launch_bounds__(512)
vq_final(const float* __restrict__ slabs, const float* __restrict__ hsum,
         const float* __restrict__ acc_loss, const float* __restrict__ ema_cs,
         const float* __restrict__ ema_w, float* __restrict__ out_scalars,
         float* __restrict__ out_cb) {
    __shared__ float sm[512];
    __shared__ float s_red[17];
    const int tid = threadIdx.x;           // tid == code k
    float cnt = hsum[tid];
    float ncs = 0.99f * ema_cs[tid] + 0.01f * cnt;
    float v1 = ncs;
    float v2 = (cnt > 0.f) ? 1.f : 0.f;
    #pragma unroll
    for (int o = 32; o > 0; o >>= 1) {
        v1 += __shfl_down(v1, o, 64);
        v2 += __shfl_down(v2, o, 64);
    }
    const int wv = tid >> 6;
    if ((tid & 63) == 0) { s_red[wv] = v1; s_red[wv + 8] = v2; }
    __syncthreads();
    if (tid == 0) {
        float nn = 0.f, uq = 0.f;
        #pragma unroll
        for (int i = 0; i < 8; ++i) { nn += s_red[i]; uq += s_red[i + 8]; }
        s_red[16] = nn;
        if (blockIdx.x == 0) {
            out_scalars[0] = acc_loss[0] / 8388608.f;
            out_scalars[1] = uq;
        }
    }
    __syncthreads();
    float nn = s_red[16];
    sm[tid] = (ncs + 1e-5f) / (nn + 512.f * 1e-5f) * nn;
    __syncthreads();
    const int e = blockIdx.x * 512 + tid;  // e = k*64 + c
    float s = 0.f;
    #pragma unroll 8
    for (int b = 0; b < 256; ++b) s += slabs[(long)b * 32768 + e];
    float nw = 0.99f * ema_w[e] + 0.01f * s;
    out_cb[e] = nw / sm[e >> 6];
}

extern "C" void kernel_launch(void* const* d_in, const int* in_sizes, int n_in,
                              void* d_out, int out_size, void* d_ws, size_t ws_size,
                              hipStream_t stream) {
    const float* x      = (const float*)d_in[0];
    const float* cb     = (const float*)d_in[1];
    const float* ema_cs = (const float*)d_in[2];
    const float* ema_w  = (const float*)d_in[3];

    float* out     = (float*)d_out;
    float* scalars = out + 8388608;
    float* out_cb  = out + 8388610;
    float* ws      = (float*)d_ws;

    // ws layout (floats):
    float* slabs    = ws;                               // 256*32768 = 8,388,608 (32MB)
    float* hsum     = slabs + 8388608;                  // 512 (+16 acc_loss, contiguous)
    float* acc_loss = hsum + 512;                       // 16
    unsigned short* bkg = (unsigned short*)(acc_loss + 16);  // 131072 u16
    // total ~33.8 MB (R4 proved >= 34.6 MB available)

    vq_argmin<<<128, 1024, AM_LDS_FLOATS * sizeof(float), stream>>>(x, cb, bkg, hsum);
    vq_fused<<<512, 512, 0, stream>>>(x, cb, bkg, out, hsum, acc_loss, slabs);
    vq_final<<<64, 512, 0, stream>>>(slabs, hsum, acc_loss, ema_cs, ema_w, scalars, out_cb);
}

// Round 12
// 193.235 us; speedup vs baseline: 1.0041x; 1.0020x over previous
//
#include <hip/hip_runtime.h>

// VQ-VAE vector quantizer: B=32,C=64,H=64,W=64, K=512, DECAY=0.99, EPS=1e-5
// N = 131072 vectors, dim 64.
// R12 = R10/R11 with the REAL spill fix. Empirical launch_bounds semantics on
// this toolchain (R6/R9/R10/R11 VGPR evidence): 2nd arg = min BLOCKS per CU
// (CUDA-style). (1024,4) -> 64 waves/CU -> 8 waves/SIMD -> 64-VGPR cap -> spill.
// (1024,1) -> 16 waves/CU -> 4 waves/SIMD -> 128-VGPR cap; R9 body needs ~100.
// Everything else identical to R11.

typedef __attribute__((ext_vector_type(8))) short bf16x8;
typedef __attribute__((ext_vector_type(16))) float f32x16;

#define MFMA32 __builtin_amdgcn_mfma_f32_32x32x16_bf16

__device__ __forceinline__ unsigned short f2bf(float f) {
    unsigned u = __float_as_uint(f);
    return (unsigned short)((u + 0x7fffu + ((u >> 16) & 1u)) >> 16);
}
__device__ __forceinline__ float bf2f(unsigned short h) {
    return __uint_as_float(((unsigned)h) << 16);
}

// top-2 update; kq ascending -> strict < keeps first (numpy argmin semantics)
__device__ __forceinline__ void upd(float s, int kq, float& b1, int& q1, float& b2, int& q2) {
    bool t1 = s < b1;
    bool t2 = s < b2;
    float nb2 = t1 ? b1 : (t2 ? s : b2);
    int   nq2 = t1 ? q1 : (t2 ? kq : q2);
    b2 = nb2; q2 = nq2;
    b1 = t1 ? s : b1;
    q1 = t1 ? kq : q1;
}

// exact fp32 re-decision between k1,k2 (R2/R9-proven ordering)
__device__ __forceinline__ int refine_pair(int k1, int k2, long gx,
        const float* __restrict__ x, const float* __restrict__ cbg,
        const float* esq) {
    const float4* e1 = (const float4*)(cbg + (k1 << 6));
    const float4* e2 = (const float4*)(cbg + (k2 << 6));
    float a0 = 0.f, a1 = 0.f, c0 = 0.f, c1 = 0.f;
    #pragma unroll 4
    for (int j = 0; j < 16; ++j) {
        float4 ea = e1[j], eb = e2[j];
        float x0 = x[gx + (long)(4 * j + 0) * 4096];
        float x1 = x[gx + (long)(4 * j + 1) * 4096];
        float x2 = x[gx + (long)(4 * j + 2) * 4096];
        float x3 = x[gx + (long)(4 * j + 3) * 4096];
        a0 = fmaf(x0, ea.x, a0); a1 = fmaf(x1, ea.y, a1);
        a0 = fmaf(x2, ea.z, a0); a1 = fmaf(x3, ea.w, a1);
        c0 = fmaf(x0, eb.x, c0); c1 = fmaf(x1, eb.y, c1);
        c0 = fmaf(x2, eb.z, c0); c1 = fmaf(x3, eb.w, c1);
    }
    float s1 = esq[k1] - 2.f * (a0 + a1);
    float s2 = esq[k2] - 2.f * (c0 + c1);
    return (s2 < s1 || (s2 == s1 && k2 < k1)) ? k2 : k1;
}

// LDS: cbhi 16384 fl | cblo 16384 fl | esq 512 fl = 133,120 B; 1024 thr, 1 block/CU
#define AM_LDS_FLOATS 33280

__global__ void __launch_bounds__(1024, 1)
vq_argmin(const float* __restrict__ x, const float* __restrict__ cbg,
          unsigned short* __restrict__ bkg, float* __restrict__ zero528) {
    extern __shared__ float lds[];
    float* esq = lds + 32768;
    bf16x8* chi = (bf16x8*)lds;
    bf16x8* clo = (bf16x8*)(lds + 16384);
    const int tid  = threadIdx.x;
    const int lane = tid & 63;
    const int wv   = tid >> 6;     // 0..15
    const int l31  = lane & 31;
    const int hh   = lane >> 5;

    // ---- fused prep: thread t < 512 converts codebook row t (c ascending:
    //      esq fmaf order == proven prep order) ----
    if (tid < 512) {
        const float4* rowp = (const float4*)(cbg + (tid << 6));
        float s = 0.f;
        #pragma unroll
        for (int u = 0; u < 8; ++u) {
            float4 va = rowp[u * 2], vb = rowp[u * 2 + 1];
            const float v[8] = {va.x, va.y, va.z, va.w, vb.x, vb.y, vb.z, vb.w};
            bf16x8 h8, l8;
            #pragma unroll
            for (int j = 0; j < 8; ++j) {
                float e = v[j];
                s = fmaf(e, e, s);
                unsigned short hb = f2bf(e);
                float lo = e - bf2f(hb);
                h8[j] = (short)hb;
                l8[j] = (short)f2bf(lo);
            }
            chi[u * 512 + tid] = h8;
            clo[u * 512 + tid] = l8;
        }
        esq[tid] = s;
    }
    // zero hsum(512)+acc_loss(16): all blocks write 0 -- race-safe, done before consumers
    if (tid < 528) zero528[tid] = 0.f;

    // ---- B build: 2 n-tiles per wave (-2x, hi/lo via cvt_pk; R9-proven) ----
    const int nb = blockIdx.x * 1024 + wv * 64;
    bf16x8 B0h[4], B0l[4], B1h[4], B1l[4];
    #pragma unroll
    for (int ct = 0; ct < 2; ++ct) {
        const int n = nb + ct * 32 + l31;
        const long gx = (long)(n >> 12) * 262144 + (long)((n >> 6) & 63) * 64 + (n & 63);
        #pragma unroll
        for (int cs = 0; cs < 4; ++cs) {
            float v[8];
            #pragma unroll
            for (int j = 0; j < 8; ++j)
                v[j] = -2.f * x[gx + (long)(cs * 16 + hh * 8 + j) * 4096];
            union { unsigned u[4]; bf16x8 v8; } uh, ul;
            #pragma unroll
            for (int p = 0; p < 4; ++p) {
                unsigned hp, lp;
                asm("v_cvt_pk_bf16_f32 %0, %1, %2" : "=v"(hp) : "v"(v[2*p]), "v"(v[2*p+1]));
                float r0 = v[2*p]     - __uint_as_float(hp << 16);
                float r1 = v[2*p + 1] - __uint_as_float(hp & 0xFFFF0000u);
                asm("v_cvt_pk_bf16_f32 %0, %1, %2" : "=v"(lp) : "v"(r0), "v"(r1));
                uh.u[p] = hp; ul.u[p] = lp;
            }
            if (ct == 0) { B0h[cs] = uh.v8; B0l[cs] = ul.v8; }
            else         { B1h[cs] = uh.v8; B1l[cs] = ul.v8; }
        }
    }
    __syncthreads();

    // ---- K loop: 16 tiles x 32 codes, 2-deep A ping-pong, esq in acc-init ----
    float b1a = 3.4e38f, b2a = 3.4e38f, b1b = 3.4e38f, b2b = 3.4e38f;
    int   q1a = 0, q2a = 0, q1b = 0, q2b = 0;
    bf16x8 Xh[4], Xl[4], Yh[4], Yl[4];

#define LOADA(Ah, Al, kt) { _Pragma("unroll") for (int cs = 0; cs < 4; ++cs) { \
        const int fi = (cs * 2 + hh) * 512 + (kt) * 32 + l31; \
        Ah[cs] = chi[fi]; Al[cs] = clo[fi]; } }

#define STEP(Ah, Al, kt) { \
        f32x16 acc0, acc1; \
        _Pragma("unroll") for (int g = 0; g < 4; ++g) { \
            float4 e4 = *(const float4*)(esq + (kt) * 32 + 8 * g + 4 * hh); \
            acc0[4*g] = e4.x; acc0[4*g+1] = e4.y; acc0[4*g+2] = e4.z; acc0[4*g+3] = e4.w; \
            acc1[4*g] = e4.x; acc1[4*g+1] = e4.y; acc1[4*g+2] = e4.z; acc1[4*g+3] = e4.w; } \
        _Pragma("unroll") for (int cs = 0; cs < 4; ++cs) { \
            acc0 = MFMA32(Ah[cs], B0h[cs], acc0, 0, 0, 0); \
            acc1 = MFMA32(Ah[cs], B1h[cs], acc1, 0, 0, 0); \
            acc0 = MFMA32(Al[cs], B0h[cs], acc0, 0, 0, 0); \
            acc1 = MFMA32(Al[cs], B1h[cs], acc1, 0, 0, 0); \
            acc0 = MFMA32(Ah[cs], B0l[cs], acc0, 0, 0, 0); \
            acc1 = MFMA32(Ah[cs], B1l[cs], acc1, 0, 0, 0); } \
        _Pragma("unroll") for (int e = 0; e < 16; ++e) { \
            int kq = (kt) * 32 + (e & 3) + 8 * (e >> 2); \
            upd(acc0[e], kq, b1a, q1a, b2a, q2a); \
            upd(acc1[e], kq, b1b, q1b, b2b, q2b); } }

    LOADA(Xh, Xl, 0)
    #pragma unroll 1
    for (int ktp = 0; ktp < 16; ktp += 2) {
        LOADA(Yh, Yl, ktp + 1)
        STEP(Xh, Xl, ktp)
        if (ktp + 2 < 16) LOADA(Xh, Xl, ktp + 2)
        STEP(Yh, Yl, ktp + 1)
    }

    // ---- merge hh halves (true k = kq + 4*hh) + in-kernel refine + final bkg ----
#define MERGE(b1, q1, b2, q2, ct) { \
        float mb1 = b1, mb2 = b2; int mk1 = q1 + 4 * hh, mk2 = q2 + 4 * hh; \
        float ob1 = __shfl_xor(mb1, 32, 64); int ok1 = __shfl_xor(mk1, 32, 64); \
        float ob2 = __shfl_xor(mb2, 32, 64); int ok2 = __shfl_xor(mk2, 32, 64); \
        bool t = (ob1 < mb1) || (ob1 == mb1 && ok1 < mk1); \
        float w1 = t ? ob1 : mb1;  int wk1 = t ? ok1 : mk1; \
        float l1 = t ? mb1 : ob1;  int lk1 = t ? mk1 : ok1; \
        float w2c = t ? ob2 : mb2; int wk2c = t ? ok2 : mk2; \
        bool t2 = (w2c < l1) || (w2c == l1 && wk2c < lk1); \
        float w2 = t2 ? w2c : l1;  int wk2 = t2 ? wk2c : lk1; \
        if (hh == 0) { \
            int kk = wk1; \
            if (wk2 != wk1 && (w2 - w1 < 2e-3f)) { \
                const int n = nb + (ct) * 32 + l31; \
                const long gx = (long)(n >> 12) * 262144 \
                              + (long)((n >> 6) & 63) * 64 + (n & 63); \
                kk = refine_pair(wk1, wk2, gx, x, cbg, esq); \
            } \
            bkg[nb + (ct) * 32 + l31] = (unsigned short)kk; } }

    MERGE(b1a, q1a, b2a, q2a, 0)
    MERGE(b1b, q1b, b2b, q2b, 1)
#undef LOADA
#undef STEP
#undef MERGE
}

// ---- fused consumers of bkg: blocks 0-255 out/loss/hist, 256-511 segsum GEMM ----
__global__ void __launch_bounds__(512)
vq_fused(const float* __restrict__ x, const float* __restrict__ cbg,
         const unsigned short* __restrict__ bkg, float* __restrict__ out,
         float* __restrict__ hsum, float* __restrict__ acc_loss,
         float* __restrict__ slabs) {
    __shared__ float hist[512];
    __shared__ float lred[8];
    const int tid = threadIdx.x;
    if (blockIdx.x < 256) {
        // ---- out (= q, == x+(q-x) to 1 ulp, R5-proven) + loss + counts ----
        hist[tid] = 0.f;
        __syncthreads();
        const int n  = blockIdx.x * 512 + tid;
        const long gx = (long)(n >> 12) * 262144 + (long)((n >> 6) & 63) * 64 + (n & 63);
        const int k1 = bkg[n];
        atomicAdd(&hist[k1], 1.0f);
        const float4* q4 = (const float4*)(cbg + (k1 << 6));
        float lsum = 0.f;
        #pragma unroll
        for (int j = 0; j < 16; ++j) {
            float4 q = q4[j];
            const float qv[4] = {q.x, q.y, q.z, q.w};
            #pragma unroll
            for (int r = 0; r < 4; ++r) {
                const int c = 4 * j + r;
                float xc = x[gx + (long)c * 4096];
                out[gx + (long)c * 4096] = qv[r];
                float d = xc - qv[r];
                lsum = fmaf(d, d, lsum);
            }
        }
        #pragma unroll
        for (int o = 32; o > 0; o >>= 1) lsum += __shfl_down(lsum, o, 64);
        if ((tid & 63) == 0) lred[tid >> 6] = lsum;
        __syncthreads();
        if (tid == 0) {
            float l = ((lred[0] + lred[1]) + (lred[2] + lred[3]))
                    + ((lred[4] + lred[5]) + (lred[6] + lred[7]));
            atomicAdd(acc_loss, l);
        }
        { float v = hist[tid]; if (v != 0.f) atomicAdd(&hsum[tid], v); }
    } else {
        // ---- segment sum as onehot MFMA GEMM (R9-proven, zero atomics) ----
        const int lane = tid & 63;
        const int w    = tid >> 6;
        const int l31  = lane & 31;
        const int hh   = lane >> 5;
        const int bix  = blockIdx.x - 256;
        const int n0   = bix * 512;
        const float* xpl = x + (long)(n0 >> 12) * 262144 + (n0 & 4095);
        const int t0 = w * 32 + l31;
        const int t1 = (w + 8) * 32 + l31;
        f32x16 aA0 = {}, aA1 = {}, aB0 = {}, aB1 = {};

        #pragma unroll 1
        for (int b16 = 0; b16 < 32; ++b16) {
            const int nofs = b16 * 16 + hh * 8;
            bf16x8 Bf0, Bf1;
            const float* p0 = xpl + (long)l31 * 4096 + nofs;
            const float* p1 = xpl + (long)(32 + l31) * 4096 + nofs;
            #pragma unroll
            for (int j = 0; j < 8; ++j) {
                Bf0[j] = (short)f2bf(p0[j]);
                Bf1[j] = (short)f2bf(p1[j]);
            }
            bf16x8 A0, A1;
            const unsigned short* kp = bkg + n0 + nofs;
            #pragma unroll
            for (int j = 0; j < 8; ++j) {
                const int k = kp[j];
                A0[j] = (k == t0) ? (short)0x3F80 : (short)0;
                A1[j] = (k == t1) ? (short)0x3F80 : (short)0;
            }
            aA0 = MFMA32(A0, Bf0, aA0, 0, 0, 0);
            aA1 = MFMA32(A0, Bf1, aA1, 0, 0, 0);
            aB0 = MFMA32(A1, Bf0, aB0, 0, 0, 0);
            aB1 = MFMA32(A1, Bf1, aB1, 0, 0, 0);
        }
        float* slab = slabs + (long)bix * 32768;
        #pragma unroll
        for (int e = 0; e < 16; ++e) {
            const int row = (e & 3) + 8 * (e >> 2) + 4 * hh;
            slab[(w * 32 + row) * 64 + l31]            = aA0[e];
            slab[(w * 32 + row) * 64 + 32 + l31]       = aA1[e];
            slab[((w + 8) * 32 + row) * 64 + l31]      = aB0[e];
            slab[((w + 8) * 32 + row) * 64 + 32 + l31] = aB1[e];
        }
    }
}

// ---- final: scalars (block 0) + codebook; smoothed recomputed per block ----
__global__ void __launch_bounds__(512)
vq_final(const float* __restrict__ slabs, const float* __restrict__ hsum,
         const float* __restrict__ acc_loss, const float* __restrict__ ema_cs,
         const float* __restrict__ ema_w, float* __restrict__ out_scalars,
         float* __restrict__ out_cb) {
    __shared__ float sm[512];
    __shared__ float s_red[17];
    const int tid = threadIdx.x;           // tid == code k
    float cnt = hsum[tid];
    float ncs = 0.99f * ema_cs[tid] + 0.01f * cnt;
    float v1 = ncs;
    float v2 = (cnt > 0.f) ? 1.f : 0.f;
    #pragma unroll
    for (int o = 32; o > 0; o >>= 1) {
        v1 += __shfl_down(v1, o, 64);
        v2 += __shfl_down(v2, o, 64);
    }
    const int wv = tid >> 6;
    if ((tid & 63) == 0) { s_red[wv] = v1; s_red[wv + 8] = v2; }
    __syncthreads();
    if (tid == 0) {
        float nn = 0.f, uq = 0.f;
        #pragma unroll
        for (int i = 0; i < 8; ++i) { nn += s_red[i]; uq += s_red[i + 8]; }
        s_red[16] = nn;
        if (blockIdx.x == 0) {
            out_scalars[0] = acc_loss[0] / 8388608.f;
            out_scalars[1] = uq;
        }
    }
    __syncthreads();
    float nn = s_red[16];
    sm[tid] = (ncs + 1e-5f) / (nn + 512.f * 1e-5f) * nn;
    __syncthreads();
    const int e = blockIdx.x * 512 + tid;  // e = k*64 + c
    float s = 0.f;
    #pragma unroll 8
    for (int b = 0; b < 256; ++b) s += slabs[(long)b * 32768 + e];
    float nw = 0.99f * ema_w[e] + 0.01f * s;
    out_cb[e] = nw / sm[e >> 6];
}

extern "C" void kernel_launch(void* const* d_in, const int* in_sizes, int n_in,
                              void* d_out, int out_size, void* d_ws, size_t ws_size,
                              hipStream_t stream) {
    const float* x      = (const float*)d_in[0];
    const float* cb     = (const float*)d_in[1];
    const float* ema_cs = (const float*)d_in[2];
    const float* ema_w  = (const float*)d_in[3];

    float* out     = (float*)d_out;
    float* scalars = out + 8388608;
    float* out_cb  = out + 8388610;
    float* ws      = (float*)d_ws;

    // ws layout (floats):
    float* slabs    = ws;                               // 256*32768 = 8,388,608 (32MB)
    float* hsum     = slabs + 8388608;                  // 512 (+16 acc_loss, contiguous)
    float* acc_loss = hsum + 512;                       // 16
    unsigned short* bkg = (unsigned short*)(acc_loss + 16);  // 131072 u16
    // total ~33.8 MB (R4 proved >= 34.6 MB available)

    vq_argmin<<<128, 1024, AM_LDS_FLOATS * sizeof(float), stream>>>(x, cb, bkg, hsum);
    vq_fused<<<512, 512, 0, stream>>>(x, cb, bkg, out, hsum, acc_loss, slabs);
    vq_final<<<64, 512, 0, stream>>>(slabs, hsum, acc_loss, ema_cs, ema_w, scalars, out_cb);
}

// Round 14
// 109.226 us; speedup vs baseline: 1.7765x; 1.7691x over previous
//
#include <hip/hip_runtime.h>

// VQ-VAE vector quantizer: B=32,C=64,H=64,W=64, K=512, DECAY=0.99, EPS=1e-5
// N = 131072 vectors, dim 64.
// R14 = R13 with the replay-determinism fix: at 512 threads the zeroing
// `if (tid<528)` never touched elements 512..527 (acc_loss) -> loss accumulated
// across graph replays (first call passed, re-validation failed). Now all 528
// floats (hsum+acc_loss) are zeroed from 512 threads. Everything else = R13.

typedef __attribute__((ext_vector_type(8))) short bf16x8;
typedef __attribute__((ext_vector_type(16))) float f32x16;

#define MFMA32 __builtin_amdgcn_mfma_f32_32x32x16_bf16

__device__ __forceinline__ unsigned short f2bf(float f) {
    unsigned u = __float_as_uint(f);
    return (unsigned short)((u + 0x7fffu + ((u >> 16) & 1u)) >> 16);
}
__device__ __forceinline__ float bf2f(unsigned short h) {
    return __uint_as_float(((unsigned)h) << 16);
}

// top-2 update; kq ascending -> strict < keeps first (numpy argmin semantics)
__device__ __forceinline__ void upd(float s, int kq, float& b1, int& q1, float& b2, int& q2) {
    bool t1 = s < b1;
    bool t2 = s < b2;
    float nb2 = t1 ? b1 : (t2 ? s : b2);
    int   nq2 = t1 ? q1 : (t2 ? kq : q2);
    b2 = nb2; q2 = nq2;
    b1 = t1 ? s : b1;
    q1 = t1 ? kq : q1;
}

// exact fp32 re-decision between k1,k2 (R2/R9-proven ordering)
__device__ __forceinline__ int refine_pair(int k1, int k2, long gx,
        const float* __restrict__ x, const float* __restrict__ cbg,
        const float* esq) {
    const float4* e1 = (const float4*)(cbg + (k1 << 6));
    const float4* e2 = (const float4*)(cbg + (k2 << 6));
    float a0 = 0.f, a1 = 0.f, c0 = 0.f, c1 = 0.f;
    #pragma unroll 4
    for (int j = 0; j < 16; ++j) {
        float4 ea = e1[j], eb = e2[j];
        float x0 = x[gx + (long)(4 * j + 0) * 4096];
        float x1 = x[gx + (long)(4 * j + 1) * 4096];
        float x2 = x[gx + (long)(4 * j + 2) * 4096];
        float x3 = x[gx + (long)(4 * j + 3) * 4096];
        a0 = fmaf(x0, ea.x, a0); a1 = fmaf(x1, ea.y, a1);
        a0 = fmaf(x2, ea.z, a0); a1 = fmaf(x3, ea.w, a1);
        c0 = fmaf(x0, eb.x, c0); c1 = fmaf(x1, eb.y, c1);
        c0 = fmaf(x2, eb.z, c0); c1 = fmaf(x3, eb.w, c1);
    }
    float s1 = esq[k1] - 2.f * (a0 + a1);
    float s2 = esq[k2] - 2.f * (c0 + c1);
    return (s2 < s1 || (s2 == s1 && k2 < k1)) ? k2 : k1;
}

// LDS: cbhi 16384 fl | cblo 16384 fl | esq 512 fl = 133,120 B; 512 thr, 1 block/CU
#define AM_LDS_FLOATS 33280

__global__ void __launch_bounds__(512, 1)
vq_argmin(const float* __restrict__ x, const float* __restrict__ cbg,
          unsigned short* __restrict__ bkg, float* __restrict__ zero528) {
    extern __shared__ float lds[];
    float* esq = lds + 32768;
    bf16x8* chi = (bf16x8*)lds;
    bf16x8* clo = (bf16x8*)(lds + 16384);
    const int tid  = threadIdx.x;
    const int lane = tid & 63;
    const int wv   = tid >> 6;     // 0..7
    const int l31  = lane & 31;
    const int hh   = lane >> 5;

    // ---- fused prep: thread t converts codebook row t (c ascending:
    //      esq fmaf order == proven prep order) ----
    {
        const float4* rowp = (const float4*)(cbg + (tid << 6));
        float s = 0.f;
        #pragma unroll
        for (int u = 0; u < 8; ++u) {
            float4 va = rowp[u * 2], vb = rowp[u * 2 + 1];
            const float v[8] = {va.x, va.y, va.z, va.w, vb.x, vb.y, vb.z, vb.w};
            bf16x8 h8, l8;
            #pragma unroll
            for (int j = 0; j < 8; ++j) {
                float e = v[j];
                s = fmaf(e, e, s);
                unsigned short hb = f2bf(e);
                float lo = e - bf2f(hb);
                h8[j] = (short)hb;
                l8[j] = (short)f2bf(lo);
            }
            chi[u * 512 + tid] = h8;
            clo[u * 512 + tid] = l8;
        }
        esq[tid] = s;
    }
    // zero hsum(512)+acc_loss(16): ALL 528 floats covered from 512 threads.
    // All blocks write 0 -- race-safe, complete before the consumer kernel runs.
    zero528[tid] = 0.f;
    if (tid < 16) zero528[512 + tid] = 0.f;

    // ---- B build: 2 n-tiles per wave (-2x, hi/lo via cvt_pk; R9-proven) ----
    const int nb = blockIdx.x * 512 + wv * 64;
    bf16x8 B0h[4], B0l[4], B1h[4], B1l[4];
    #pragma unroll
    for (int ct = 0; ct < 2; ++ct) {
        const int n = nb + ct * 32 + l31;
        const long gx = (long)(n >> 12) * 262144 + (long)((n >> 6) & 63) * 64 + (n & 63);
        #pragma unroll
        for (int cs = 0; cs < 4; ++cs) {
            float v[8];
            #pragma unroll
            for (int j = 0; j < 8; ++j)
                v[j] = -2.f * x[gx + (long)(cs * 16 + hh * 8 + j) * 4096];
            union { unsigned u[4]; bf16x8 v8; } uh, ul;
            #pragma unroll
            for (int p = 0; p < 4; ++p) {
                unsigned hp, lp;
                asm("v_cvt_pk_bf16_f32 %0, %1, %2" : "=v"(hp) : "v"(v[2*p]), "v"(v[2*p+1]));
                float r0 = v[2*p]     - __uint_as_float(hp << 16);
                float r1 = v[2*p + 1] - __uint_as_float(hp & 0xFFFF0000u);
                asm("v_cvt_pk_bf16_f32 %0, %1, %2" : "=v"(lp) : "v"(r0), "v"(r1));
                uh.u[p] = hp; ul.u[p] = lp;
            }
            if (ct == 0) { B0h[cs] = uh.v8; B0l[cs] = ul.v8; }
            else         { B1h[cs] = uh.v8; B1l[cs] = ul.v8; }
        }
    }
    __syncthreads();

    // ---- K loop: 16 tiles x 32 codes, 2-deep A ping-pong, esq in acc-init ----
    float b1a = 3.4e38f, b2a = 3.4e38f, b1b = 3.4e38f, b2b = 3.4e38f;
    int   q1a = 0, q2a = 0, q1b = 0, q2b = 0;
    bf16x8 Xh[4], Xl[4], Yh[4], Yl[4];

#define LOADA(Ah, Al, kt) { _Pragma("unroll") for (int cs = 0; cs < 4; ++cs) { \
        const int fi = (cs * 2 + hh) * 512 + (kt) * 32 + l31; \
        Ah[cs] = chi[fi]; Al[cs] = clo[fi]; } }

#define STEP(Ah, Al, kt) { \
        f32x16 acc0, acc1; \
        _Pragma("unroll") for (int g = 0; g < 4; ++g) { \
            float4 e4 = *(const float4*)(esq + (kt) * 32 + 8 * g + 4 * hh); \
            acc0[4*g] = e4.x; acc0[4*g+1] = e4.y; acc0[4*g+2] = e4.z; acc0[4*g+3] = e4.w; \
            acc1[4*g] = e4.x; acc1[4*g+1] = e4.y; acc1[4*g+2] = e4.z; acc1[4*g+3] = e4.w; } \
        _Pragma("unroll") for (int cs = 0; cs < 4; ++cs) { \
            acc0 = MFMA32(Ah[cs], B0h[cs], acc0, 0, 0, 0); \
            acc1 = MFMA32(Ah[cs], B1h[cs], acc1, 0, 0, 0); \
            acc0 = MFMA32(Al[cs], B0h[cs], acc0, 0, 0, 0); \
            acc1 = MFMA32(Al[cs], B1h[cs], acc1, 0, 0, 0); \
            acc0 = MFMA32(Ah[cs], B0l[cs], acc0, 0, 0, 0); \
            acc1 = MFMA32(Ah[cs], B1l[cs], acc1, 0, 0, 0); } \
        _Pragma("unroll") for (int e = 0; e < 16; ++e) { \
            int kq = (kt) * 32 + (e & 3) + 8 * (e >> 2); \
            upd(acc0[e], kq, b1a, q1a, b2a, q2a); \
            upd(acc1[e], kq, b1b, q1b, b2b, q2b); } }

    LOADA(Xh, Xl, 0)
    #pragma unroll 1
    for (int ktp = 0; ktp < 16; ktp += 2) {
        LOADA(Yh, Yl, ktp + 1)
        STEP(Xh, Xl, ktp)
        if (ktp + 2 < 16) LOADA(Xh, Xl, ktp + 2)
        STEP(Yh, Yl, ktp + 1)
    }

    // ---- merge hh halves (true k = kq + 4*hh) + in-kernel refine + final bkg ----
#define MERGE(b1, q1, b2, q2, ct) { \
        float mb1 = b1, mb2 = b2; int mk1 = q1 + 4 * hh, mk2 = q2 + 4 * hh; \
        float ob1 = __shfl_xor(mb1, 32, 64); int ok1 = __shfl_xor(mk1, 32, 64); \
        float ob2 = __shfl_xor(mb2, 32, 64); int ok2 = __shfl_xor(mk2, 32, 64); \
        bool t = (ob1 < mb1) || (ob1 == mb1 && ok1 < mk1); \
        float w1 = t ? ob1 : mb1;  int wk1 = t ? ok1 : mk1; \
        float l1 = t ? mb1 : ob1;  int lk1 = t ? mk1 : ok1; \
        float w2c = t ? ob2 : mb2; int wk2c = t ? ok2 : mk2; \
        bool t2 = (w2c < l1) || (w2c == l1 && wk2c < lk1); \
        float w2 = t2 ? w2c : l1;  int wk2 = t2 ? wk2c : lk1; \
        if (hh == 0) { \
            int kk = wk1; \
            if (wk2 != wk1 && (w2 - w1 < 2e-3f)) { \
                const int n = nb + (ct) * 32 + l31; \
                const long gx = (long)(n >> 12) * 262144 \
                              + (long)((n >> 6) & 63) * 64 + (n & 63); \
                kk = refine_pair(wk1, wk2, gx, x, cbg, esq); \
            } \
            bkg[nb + (ct) * 32 + l31] = (unsigned short)kk; } }

    MERGE(b1a, q1a, b2a, q2a, 0)
    MERGE(b1b, q1b, b2b, q2b, 1)
#undef LOADA
#undef STEP
#undef MERGE
}

// ---- fused consumers of bkg: blocks 0-255 out/loss/hist, 256-511 segsum GEMM ----
__global__ void __launch_bounds__(512)
vq_fused(const float* __restrict__ x, const float* __restrict__ cbg,
         const unsigned short* __restrict__ bkg, float* __restrict__ out,
         float* __restrict__ hsum, float* __restrict__ acc_loss,
         float* __restrict__ slabs) {
    __shared__ float hist[512];
    __shared__ float lred[8];
    const int tid = threadIdx.x;
    if (blockIdx.x < 256) {
        // ---- out (= q, == x+(q-x) to 1 ulp, R5-proven) + loss + counts ----
        hist[tid] = 0.f;
        __syncthreads();
        const int n  = blockIdx.x * 512 + tid;
        const long gx = (long)(n >> 12) * 262144 + (long)((n >> 6) & 63) * 64 + (n & 63);
        const int k1 = bkg[n];
        atomicAdd(&hist[k1], 1.0f);
        const float4* q4 = (const float4*)(cbg + (k1 << 6));
        float lsum = 0.f;
        #pragma unroll
        for (int j = 0; j < 16; ++j) {
            float4 q = q4[j];
            const float qv[4] = {q.x, q.y, q.z, q.w};
            #pragma unroll
            for (int r = 0; r < 4; ++r) {
                const int c = 4 * j + r;
                float xc = x[gx + (long)c * 4096];
                out[gx + (long)c * 4096] = qv[r];
                float d = xc - qv[r];
                lsum = fmaf(d, d, lsum);
            }
        }
        #pragma unroll
        for (int o = 32; o > 0; o >>= 1) lsum += __shfl_down(lsum, o, 64);
        if ((tid & 63) == 0) lred[tid >> 6] = lsum;
        __syncthreads();
        if (tid == 0) {
            float l = ((lred[0] + lred[1]) + (lred[2] + lred[3]))
                    + ((lred[4] + lred[5]) + (lred[6] + lred[7]));
            atomicAdd(acc_loss, l);
        }
        { float v = hist[tid]; if (v != 0.f) atomicAdd(&hsum[tid], v); }
    } else {
        // ---- segment sum as onehot MFMA GEMM (R9-proven, zero atomics) ----
        const int lane = tid & 63;
        const int w    = tid >> 6;
        const int l31  = lane & 31;
        const int hh   = lane >> 5;
        const int bix  = blockIdx.x - 256;
        const int n0   = bix * 512;
        const float* xpl = x + (long)(n0 >> 12) * 262144 + (n0 & 4095);
        const int t0 = w * 32 + l31;
        const int t1 = (w + 8) * 32 + l31;
        f32x16 aA0 = {}, aA1 = {}, aB0 = {}, aB1 = {};

        #pragma unroll 1
        for (int b16 = 0; b16 < 32; ++b16) {
            const int nofs = b16 * 16 + hh * 8;
            bf16x8 Bf0, Bf1;
            const float* p0 = xpl + (long)l31 * 4096 + nofs;
            const float* p1 = xpl + (long)(32 + l31) * 4096 + nofs;
            #pragma unroll
            for (int j = 0; j < 8; ++j) {
                Bf0[j] = (short)f2bf(p0[j]);
                Bf1[j] = (short)f2bf(p1[j]);
            }
            bf16x8 A0, A1;
            const unsigned short* kp = bkg + n0 + nofs;
            #pragma unroll
            for (int j = 0; j < 8; ++j) {
                const int k = kp[j];
                A0[j] = (k == t0) ? (short)0x3F80 : (short)0;
                A1[j] = (k == t1) ? (short)0x3F80 : (short)0;
            }
            aA0 = MFMA32(A0, Bf0, aA0, 0, 0, 0);
            aA1 = MFMA32(A0, Bf1, aA1, 0, 0, 0);
            aB0 = MFMA32(A1, Bf0, aB0, 0, 0, 0);
            aB1 = MFMA32(A1, Bf1, aB1, 0, 0, 0);
        }
        float* slab = slabs + (long)bix * 32768;
        #pragma unroll
        for (int e = 0; e < 16; ++e) {
            const int row = (e & 3) + 8 * (e >> 2) + 4 * hh;
            slab[(w * 32 + row) * 64 + l31]            = aA0[e];
            slab[(w * 32 + row) * 64 + 32 + l31]       = aA1[e];
            slab[((w + 8) * 32 + row) * 64 + l31]      = aB0[e];
            slab[((w + 8) * 32 + row) * 64 + 32 + l31] = aB1[e];
        }
    }
}

// ---- final: scalars (block 0) + codebook; smoothed recomputed per block ----
__global__ void __launch_bounds__(512)
vq_final(const float* __restrict__ slabs, const float* __restrict__ hsum,
         const float* __restrict__ acc_loss, const float* __restrict__ ema_cs,
         const float* __restrict__ ema_w, float* __restrict__ out_scalars,
         float* __restrict__ out_cb) {
    __shared__ float sm[512];
    __shared__ float s_red[17];
    const int tid = threadIdx.x;           // tid == code k
    float cnt = hsum[tid];
    float ncs = 0.99f * ema_cs[tid] + 0.01f * cnt;
    float v1 = ncs;
    float v2 = (cnt > 0.f) ? 1.f : 0.f;
    #pragma unroll
    for (int o = 32; o > 0; o >>= 1) {
        v1 += __shfl_down(v1, o, 64);
        v2 += __shfl_down(v2, o, 64);
    }
    const int wv = tid >> 6;
    if ((tid & 63) == 0) { s_red[wv] = v1; s_red[wv + 8] = v2; }
    __syncthreads();
    if (tid == 0) {
        float nn = 0.f, uq = 0.f;
        #pragma unroll
        for (int i = 0; i < 8; ++i) { nn += s_red[i]; uq += s_red[i + 8]; }
        s_red[16] = nn;
        if (blockIdx.x == 0) {
            out_scalars[0] = acc_loss[0] / 8388608.f;
            out_scalars[1] = uq;
        }
    }
    __syncthreads();
    float nn = s_red[16];
    sm[tid] = (ncs + 1e-5f) / (nn + 512.f * 1e-5f) * nn;
    __syncthreads();
    const int e = blockIdx.x * 512 + tid;  // e = k*64 + c
    float s = 0.f;
    #pragma unroll 8
    for (int b = 0; b < 256; ++b) s += slabs[(long)b * 32768 + e];
    float nw = 0.99f * ema_w[e] + 0.01f * s;
    out_cb[e] = nw / sm[e >> 6];
}

extern "C" void kernel_launch(void* const* d_in, const int* in_sizes, int n_in,
                              void* d_out, int out_size, void* d_ws, size_t ws_size,
                              hipStream_t stream) {
    const float* x      = (const float*)d_in[0];
    const float* cb     = (const float*)d_in[1];
    const float* ema_cs = (const float*)d_in[2];
    const float* ema_w  = (const float*)d_in[3];

    float* out     = (float*)d_out;
    float* scalars = out + 8388608;
    float* out_cb  = out + 8388610;
    float* ws      = (float*)d_ws;

    // ws layout (floats):
    float* slabs    = ws;                               // 256*32768 = 8,388,608 (32MB)
    float* hsum     = slabs + 8388608;                  // 512 (+16 acc_loss, contiguous)
    float* acc_loss = hsum + 512;                       // 16
    unsigned short* bkg = (unsigned short*)(acc_loss + 16);  // 131072 u16
    // total ~33.8 MB (R4 proved >= 34.6 MB available)

    vq_argmin<<<256, 512, AM_LDS_FLOATS * sizeof(float), stream>>>(x, cb, bkg, hsum);
    vq_fused<<<512, 512, 0, stream>>>(x, cb, bkg, out, hsum, acc_loss, slabs);
    vq_final<<<64, 512, 0, stream>>>(slabs, hsum, acc_loss, ema_cs, ema_w, scalars, out_cb);
}

// Round 15
// 89.326 us; speedup vs baseline: 2.1722x; 1.2228x over previous
//
#include <hip/hip_runtime.h>

// VQ-VAE vector quantizer: B=32,C=64,H=64,W=64, K=512, DECAY=0.99, EPS=1e-5
// N = 131072 vectors, dim 64.
// R15 = R14 with the segsum gather fix: the segsum half of vq_fused staged its
// x-tile per-WAVE from global with 64-line gathers (8x redundant: nofs is
// w-independent). Now the block stages x once to LDS as bf16 [64][516-pad]
// (coalesced float4 reads, same f2bf values -> bit-identical math) + bkg tile;
// fragment reads are ushort4 LDS loads, index reads are LDS broadcasts.
// vq_fused LDS goes dynamic (67 KB, 2 blocks/CU). argmin/final frozen at R14.

typedef __attribute__((ext_vector_type(8))) short bf16x8;
typedef __attribute__((ext_vector_type(16))) float f32x16;

#define MFMA32 __builtin_amdgcn_mfma_f32_32x32x16_bf16

__device__ __forceinline__ unsigned short f2bf(float f) {
    unsigned u = __float_as_uint(f);
    return (unsigned short)((u + 0x7fffu + ((u >> 16) & 1u)) >> 16);
}
__device__ __forceinline__ float bf2f(unsigned short h) {
    return __uint_as_float(((unsigned)h) << 16);
}

// top-2 update; kq ascending -> strict < keeps first (numpy argmin semantics)
__device__ __forceinline__ void upd(float s, int kq, float& b1, int& q1, float& b2, int& q2) {
    bool t1 = s < b1;
    bool t2 = s < b2;
    float nb2 = t1 ? b1 : (t2 ? s : b2);
    int   nq2 = t1 ? q1 : (t2 ? kq : q2);
    b2 = nb2; q2 = nq2;
    b1 = t1 ? s : b1;
    q1 = t1 ? kq : q1;
}

// exact fp32 re-decision between k1,k2 (R2/R9-proven ordering)
__device__ __forceinline__ int refine_pair(int k1, int k2, long gx,
        const float* __restrict__ x, const float* __restrict__ cbg,
        const float* esq) {
    const float4* e1 = (const float4*)(cbg + (k1 << 6));
    const float4* e2 = (const float4*)(cbg + (k2 << 6));
    float a0 = 0.f, a1 = 0.f, c0 = 0.f, c1 = 0.f;
    #pragma unroll 4
    for (int j = 0; j < 16; ++j) {
        float4 ea = e1[j], eb = e2[j];
        float x0 = x[gx + (long)(4 * j + 0) * 4096];
        float x1 = x[gx + (long)(4 * j + 1) * 4096];
        float x2 = x[gx + (long)(4 * j + 2) * 4096];
        float x3 = x[gx + (long)(4 * j + 3) * 4096];
        a0 = fmaf(x0, ea.x, a0); a1 = fmaf(x1, ea.y, a1);
        a0 = fmaf(x2, ea.z, a0); a1 = fmaf(x3, ea.w, a1);
        c0 = fmaf(x0, eb.x, c0); c1 = fmaf(x1, eb.y, c1);
        c0 = fmaf(x2, eb.z, c0); c1 = fmaf(x3, eb.w, c1);
    }
    float s1 = esq[k1] - 2.f * (a0 + a1);
    float s2 = esq[k2] - 2.f * (c0 + c1);
    return (s2 < s1 || (s2 == s1 && k2 < k1)) ? k2 : k1;
}

// LDS: cbhi 16384 fl | cblo 16384 fl | esq 512 fl = 133,120 B; 512 thr, 1 block/CU
#define AM_LDS_FLOATS 33280

__global__ void __launch_bounds__(512, 1)
vq_argmin(const float* __restrict__ x, const float* __restrict__ cbg,
          unsigned short* __restrict__ bkg, float* __restrict__ zero528) {
    extern __shared__ float lds[];
    float* esq = lds + 32768;
    bf16x8* chi = (bf16x8*)lds;
    bf16x8* clo = (bf16x8*)(lds + 16384);
    const int tid  = threadIdx.x;
    const int lane = tid & 63;
    const int wv   = tid >> 6;     // 0..7
    const int l31  = lane & 31;
    const int hh   = lane >> 5;

    // ---- fused prep: thread t converts codebook row t (c ascending) ----
    {
        const float4* rowp = (const float4*)(cbg + (tid << 6));
        float s = 0.f;
        #pragma unroll
        for (int u = 0; u < 8; ++u) {
            float4 va = rowp[u * 2], vb = rowp[u * 2 + 1];
            const float v[8] = {va.x, va.y, va.z, va.w, vb.x, vb.y, vb.z, vb.w};
            bf16x8 h8, l8;
            #pragma unroll
            for (int j = 0; j < 8; ++j) {
                float e = v[j];
                s = fmaf(e, e, s);
                unsigned short hb = f2bf(e);
                float lo = e - bf2f(hb);
                h8[j] = (short)hb;
                l8[j] = (short)f2bf(lo);
            }
            chi[u * 512 + tid] = h8;
            clo[u * 512 + tid] = l8;
        }
        esq[tid] = s;
    }
    // zero hsum(512)+acc_loss(16): ALL 528 floats covered from 512 threads.
    zero528[tid] = 0.f;
    if (tid < 16) zero528[512 + tid] = 0.f;

    // ---- B build: 2 n-tiles per wave (-2x, hi/lo via cvt_pk; R9-proven) ----
    const int nb = blockIdx.x * 512 + wv * 64;
    bf16x8 B0h[4], B0l[4], B1h[4], B1l[4];
    #pragma unroll
    for (int ct = 0; ct < 2; ++ct) {
        const int n = nb + ct * 32 + l31;
        const long gx = (long)(n >> 12) * 262144 + (long)((n >> 6) & 63) * 64 + (n & 63);
        #pragma unroll
        for (int cs = 0; cs < 4; ++cs) {
            float v[8];
            #pragma unroll
            for (int j = 0; j < 8; ++j)
                v[j] = -2.f * x[gx + (long)(cs * 16 + hh * 8 + j) * 4096];
            union { unsigned u[4]; bf16x8 v8; } uh, ul;
            #pragma unroll
            for (int p = 0; p < 4; ++p) {
                unsigned hp, lp;
                asm("v_cvt_pk_bf16_f32 %0, %1, %2" : "=v"(hp) : "v"(v[2*p]), "v"(v[2*p+1]));
                float r0 = v[2*p]     - __uint_as_float(hp << 16);
                float r1 = v[2*p + 1] - __uint_as_float(hp & 0xFFFF0000u);
                asm("v_cvt_pk_bf16_f32 %0, %1, %2" : "=v"(lp) : "v"(r0), "v"(r1));
                uh.u[p] = hp; ul.u[p] = lp;
            }
            if (ct == 0) { B0h[cs] = uh.v8; B0l[cs] = ul.v8; }
            else         { B1h[cs] = uh.v8; B1l[cs] = ul.v8; }
        }
    }
    __syncthreads();

    // ---- K loop: 16 tiles x 32 codes, 2-deep A ping-pong, esq in acc-init ----
    float b1a = 3.4e38f, b2a = 3.4e38f, b1b = 3.4e38f, b2b = 3.4e38f;
    int   q1a = 0, q2a = 0, q1b = 0, q2b = 0;
    bf16x8 Xh[4], Xl[4], Yh[4], Yl[4];

#define LOADA(Ah, Al, kt) { _Pragma("unroll") for (int cs = 0; cs < 4; ++cs) { \
        const int fi = (cs * 2 + hh) * 512 + (kt) * 32 + l31; \
        Ah[cs] = chi[fi]; Al[cs] = clo[fi]; } }

#define STEP(Ah, Al, kt) { \
        f32x16 acc0, acc1; \
        _Pragma("unroll") for (int g = 0; g < 4; ++g) { \
            float4 e4 = *(const float4*)(esq + (kt) * 32 + 8 * g + 4 * hh); \
            acc0[4*g] = e4.x; acc0[4*g+1] = e4.y; acc0[4*g+2] = e4.z; acc0[4*g+3] = e4.w; \
            acc1[4*g] = e4.x; acc1[4*g+1] = e4.y; acc1[4*g+2] = e4.z; acc1[4*g+3] = e4.w; } \
        _Pragma("unroll") for (int cs = 0; cs < 4; ++cs) { \
            acc0 = MFMA32(Ah[cs], B0h[cs], acc0, 0, 0, 0); \
            acc1 = MFMA32(Ah[cs], B1h[cs], acc1, 0, 0, 0); \
            acc0 = MFMA32(Al[cs], B0h[cs], acc0, 0, 0, 0); \
            acc1 = MFMA32(Al[cs], B1h[cs], acc1, 0, 0, 0); \
            acc0 = MFMA32(Ah[cs], B0l[cs], acc0, 0, 0, 0); \
            acc1 = MFMA32(Ah[cs], B1l[cs], acc1, 0, 0, 0); } \
        _Pragma("unroll") for (int e = 0; e < 16; ++e) { \
            int kq = (kt) * 32 + (e & 3) + 8 * (e >> 2); \
            upd(acc0[e], kq, b1a, q1a, b2a, q2a); \
            upd(acc1[e], kq, b1b, q1b, b2b, q2b); } }

    LOADA(Xh, Xl, 0)
    #pragma unroll 1
    for (int ktp = 0; ktp < 16; ktp += 2) {
        LOADA(Yh, Yl, ktp + 1)
        STEP(Xh, Xl, ktp)
        if (ktp + 2 < 16) LOADA(Xh, Xl, ktp + 2)
        STEP(Yh, Yl, ktp + 1)
    }

    // ---- merge hh halves (true k = kq + 4*hh) + in-kernel refine + final bkg ----
#define MERGE(b1, q1, b2, q2, ct) { \
        float mb1 = b1, mb2 = b2; int mk1 = q1 + 4 * hh, mk2 = q2 + 4 * hh; \
        float ob1 = __shfl_xor(mb1, 32, 64); int ok1 = __shfl_xor(mk1, 32, 64); \
        float ob2 = __shfl_xor(mb2, 32, 64); int ok2 = __shfl_xor(mk2, 32, 64); \
        bool t = (ob1 < mb1) || (ob1 == mb1 && ok1 < mk1); \
        float w1 = t ? ob1 : mb1;  int wk1 = t ? ok1 : mk1; \
        float l1 = t ? mb1 : ob1;  int lk1 = t ? mk1 : ok1; \
        float w2c = t ? ob2 : mb2; int wk2c = t ? ok2 : mk2; \
        bool t2 = (w2c < l1) || (w2c == l1 && wk2c < lk1); \
        float w2 = t2 ? w2c : l1;  int wk2 = t2 ? wk2c : lk1; \
        if (hh == 0) { \
            int kk = wk1; \
            if (wk2 != wk1 && (w2 - w1 < 2e-3f)) { \
                const int n = nb + (ct) * 32 + l31; \
                const long gx = (long)(n >> 12) * 262144 \
                              + (long)((n >> 6) & 63) * 64 + (n & 63); \
                kk = refine_pair(wk1, wk2, gx, x, cbg, esq); \
            } \
            bkg[nb + (ct) * 32 + l31] = (unsigned short)kk; } }

    MERGE(b1a, q1a, b2a, q2a, 0)
    MERGE(b1b, q1b, b2b, q2b, 1)
#undef LOADA
#undef STEP
#undef MERGE
}

// ---- fused consumers of bkg: blocks 0-255 out/loss/hist, 256-511 segsum GEMM ----
// dynamic LDS: 33536 ushort = 67,072 B (segsum: xb 64*516 + kb 512; out: 520 fl)
#define FUSED_LDS_BYTES (33536 * 2)

__global__ void __launch_bounds__(512)
vq_fused(const float* __restrict__ x, const float* __restrict__ cbg,
         const unsigned short* __restrict__ bkg, float* __restrict__ out,
         float* __restrict__ hsum, float* __restrict__ acc_loss,
         float* __restrict__ slabs) {
    extern __shared__ unsigned short sm16[];
    const int tid = threadIdx.x;
    if (blockIdx.x < 256) {
        // ---- out (= q, == x+(q-x) to 1 ulp, R5-proven) + loss + counts ----
        float* hist = (float*)sm16;          // 512 floats
        float* lred = (float*)sm16 + 512;    // 8 floats
        hist[tid] = 0.f;
        __syncthreads();
        const int n  = blockIdx.x * 512 + tid;
        const long gx = (long)(n >> 12) * 262144 + (long)((n >> 6) & 63) * 64 + (n & 63);
        const int k1 = bkg[n];
        atomicAdd(&hist[k1], 1.0f);
        const float4* q4 = (const float4*)(cbg + (k1 << 6));
        float lsum = 0.f;
        #pragma unroll
        for (int j = 0; j < 16; ++j) {
            float4 q = q4[j];
            const float qv[4] = {q.x, q.y, q.z, q.w};
            #pragma unroll
            for (int r = 0; r < 4; ++r) {
                const int c = 4 * j + r;
                float xc = x[gx + (long)c * 4096];
                out[gx + (long)c * 4096] = qv[r];
                float d = xc - qv[r];
                lsum = fmaf(d, d, lsum);
            }
        }
        #pragma unroll
        for (int o = 32; o > 0; o >>= 1) lsum += __shfl_down(lsum, o, 64);
        if ((tid & 63) == 0) lred[tid >> 6] = lsum;
        __syncthreads();
        if (tid == 0) {
            float l = ((lred[0] + lred[1]) + (lred[2] + lred[3]))
                    + ((lred[4] + lred[5]) + (lred[6] + lred[7]));
            atomicAdd(acc_loss, l);
        }
        { float v = hist[tid]; if (v != 0.f) atomicAdd(&hsum[tid], v); }
    } else {
        // ---- segment sum as onehot MFMA GEMM, LDS-staged x-tile (R9 math) ----
        unsigned short* xb = sm16;           // [64][516] bf16, 516-pad: bank-spread
        unsigned short* kb = sm16 + 33024;   // 512 indices
        const int lane = tid & 63;
        const int w    = tid >> 6;
        const int l31  = lane & 31;
        const int hh   = lane >> 5;
        const int bix  = blockIdx.x - 256;
        const int n0   = bix * 512;
        const float* xpl = x + (long)(n0 >> 12) * 262144 + (n0 & 4095);

        // stage: bkg tile (coalesced) + x tile (coalesced float4, each elem once)
        kb[tid] = bkg[n0 + tid];
        #pragma unroll
        for (int i = 0; i < 16; ++i) {
            const int f  = tid + i * 512;        // 0..8191 float4s
            const int c  = f >> 7;
            const int n4 = (f & 127) << 2;
            float4 v = *(const float4*)(xpl + (long)c * 4096 + n4);
            ushort4 o;
            o.x = f2bf(v.x); o.y = f2bf(v.y); o.z = f2bf(v.z); o.w = f2bf(v.w);
            *(ushort4*)(xb + c * 516 + n4) = o;
        }
        __syncthreads();

        const int t0 = w * 32 + l31;
        const int t1 = (w + 8) * 32 + l31;
        f32x16 aA0 = {}, aA1 = {}, aB0 = {}, aB1 = {};

        #pragma unroll 1
        for (int b16 = 0; b16 < 32; ++b16) {
            const int nofs = b16 * 16 + hh * 8;
            // B fragments from LDS (8B-aligned ushort4; <=4-way bank alias)
            ushort4 p0a = *(const ushort4*)(xb + l31 * 516 + nofs);
            ushort4 p0b = *(const ushort4*)(xb + l31 * 516 + nofs + 4);
            ushort4 p1a = *(const ushort4*)(xb + (32 + l31) * 516 + nofs);
            ushort4 p1b = *(const ushort4*)(xb + (32 + l31) * 516 + nofs + 4);
            bf16x8 Bf0, Bf1;
            Bf0[0] = (short)p0a.x; Bf0[1] = (short)p0a.y;
            Bf0[2] = (short)p0a.z; Bf0[3] = (short)p0a.w;
            Bf0[4] = (short)p0b.x; Bf0[5] = (short)p0b.y;
            Bf0[6] = (short)p0b.z; Bf0[7] = (short)p0b.w;
            Bf1[0] = (short)p1a.x; Bf1[1] = (short)p1a.y;
            Bf1[2] = (short)p1a.z; Bf1[3] = (short)p1a.w;
            Bf1[4] = (short)p1b.x; Bf1[5] = (short)p1b.y;
            Bf1[6] = (short)p1b.z; Bf1[7] = (short)p1b.w;
            // A fragments: onehot from LDS broadcast reads
            ushort4 k4a = *(const ushort4*)(kb + nofs);
            ushort4 k4b = *(const ushort4*)(kb + nofs + 4);
            const int kk[8] = {k4a.x, k4a.y, k4a.z, k4a.w,
                               k4b.x, k4b.y, k4b.z, k4b.w};
            bf16x8 A0, A1;
            #pragma unroll
            for (int j = 0; j < 8; ++j) {
                A0[j] = (kk[j] == t0) ? (short)0x3F80 : (short)0;
                A1[j] = (kk[j] == t1) ? (short)0x3F80 : (short)0;
            }
            aA0 = MFMA32(A0, Bf0, aA0, 0, 0, 0);
            aA1 = MFMA32(A0, Bf1, aA1, 0, 0, 0);
            aB0 = MFMA32(A1, Bf0, aB0, 0, 0, 0);
            aB1 = MFMA32(A1, Bf1, aB1, 0, 0, 0);
        }
        float* slab = slabs + (long)bix * 32768;
        #pragma unroll
        for (int e = 0; e < 16; ++e) {
            const int row = (e & 3) + 8 * (e >> 2) + 4 * hh;
            slab[(w * 32 + row) * 64 + l31]            = aA0[e];
            slab[(w * 32 + row) * 64 + 32 + l31]       = aA1[e];
            slab[((w + 8) * 32 + row) * 64 + l31]      = aB0[e];
            slab[((w + 8) * 32 + row) * 64 + 32 + l31] = aB1[e];
        }
    }
}

// ---- final: scalars (block 0) + codebook; smoothed recomputed per block ----
__global__ void __launch_bounds__(512)
vq_final(const float* __restrict__ slabs, const float* __restrict__ hsum,
         const float* __restrict__ acc_loss, const float* __restrict__ ema_cs,
         const float* __restrict__ ema_w, float* __restrict__ out_scalars,
         float* __restrict__ out_cb) {
    __shared__ float sm[512];
    __shared__ float s_red[17];
    const int tid = threadIdx.x;           // tid == code k
    float cnt = hsum[tid];
    float ncs = 0.99f * ema_cs[tid] + 0.01f * cnt;
    float v1 = ncs;
    float v2 = (cnt > 0.f) ? 1.f : 0.f;
    #pragma unroll
    for (int o = 32; o > 0; o >>= 1) {
        v1 += __shfl_down(v1, o, 64);
        v2 += __shfl_down(v2, o, 64);
    }
    const int wv = tid >> 6;
    if ((tid & 63) == 0) { s_red[wv] = v1; s_red[wv + 8] = v2; }
    __syncthreads();
    if (tid == 0) {
        float nn = 0.f, uq = 0.f;
        #pragma unroll
        for (int i = 0; i < 8; ++i) { nn += s_red[i]; uq += s_red[i + 8]; }
        s_red[16] = nn;
        if (blockIdx.x == 0) {
            out_scalars[0] = acc_loss[0] / 8388608.f;
            out_scalars[1] = uq;
        }
    }
    __syncthreads();
    float nn = s_red[16];
    sm[tid] = (ncs + 1e-5f) / (nn + 512.f * 1e-5f) * nn;
    __syncthreads();
    const int e = blockIdx.x * 512 + tid;  // e = k*64 + c
    float s = 0.f;
    #pragma unroll 8
    for (int b = 0; b < 256; ++b) s += slabs[(long)b * 32768 + e];
    float nw = 0.99f * ema_w[e] + 0.01f * s;
    out_cb[e] = nw / sm[e >> 6];
}

extern "C" void kernel_launch(void* const* d_in, const int* in_sizes, int n_in,
                              void* d_out, int out_size, void* d_ws, size_t ws_size,
                              hipStream_t stream) {
    const float* x      = (const float*)d_in[0];
    const float* cb     = (const float*)d_in[1];
    const float* ema_cs = (const float*)d_in[2];
    const float* ema_w  = (const float*)d_in[3];

    float* out     = (float*)d_out;
    float* scalars = out + 8388608;
    float* out_cb  = out + 8388610;
    float* ws      = (float*)d_ws;

    // ws layout (floats):
    float* slabs    = ws;                               // 256*32768 = 8,388,608 (32MB)
    float* hsum     = slabs + 8388608;                  // 512 (+16 acc_loss, contiguous)
    float* acc_loss = hsum + 512;                       // 16
    unsigned short* bkg = (unsigned short*)(acc_loss + 16);  // 131072 u16
    // total ~33.8 MB (R4 proved >= 34.6 MB available)

    vq_argmin<<<256, 512, AM_LDS_FLOATS * sizeof(float), stream>>>(x, cb, bkg, hsum);
    vq_fused<<<512, 512, FUSED_LDS_BYTES, stream>>>(x, cb, bkg, out, hsum, acc_loss, slabs);
    vq_final<<<64, 512, 0, stream>>>(slabs, hsum, acc_loss, ema_cs, ema_w, scalars, out_cb);
}

// Round 16
// 88.621 us; speedup vs baseline: 2.1895x; 1.0080x over previous
//
#include <hip/hip_runtime.h>

// VQ-VAE vector quantizer: B=32,C=64,H=64,W=64, K=512, DECAY=0.99, EPS=1e-5
// N = 131072 vectors, dim 64.
// R16: argmin occupancy attack. R15's argmin ran 1 block/CU (grid 256 = CU count)
// at 2 waves/SIMD, VALUBusy 45% -> latency-bound. Now: separate vq_prep (R9-proven,
// kills 256x redundant codebook conversion), argmin LDS halved to 66KB (hi-codebook
// + esq only; lo-codebook A-frags stream from L2-hot global with ping-pong
// prefetch), 512 blocks x 512 thr x 1 n-tile/wave -> 2 blocks/CU = 4 waves/SIMD.
// Scores bit-identical to R15. vq_fused/vq_final frozen.

typedef __attribute__((ext_vector_type(8))) short bf16x8;
typedef __attribute__((ext_vector_type(16))) float f32x16;

#define MFMA32 __builtin_amdgcn_mfma_f32_32x32x16_bf16

__device__ __forceinline__ unsigned short f2bf(float f) {
    unsigned u = __float_as_uint(f);
    return (unsigned short)((u + 0x7fffu + ((u >> 16) & 1u)) >> 16);
}
__device__ __forceinline__ float bf2f(unsigned short h) {
    return __uint_as_float(((unsigned)h) << 16);
}

// ---- prep (R9-proven): esq + split hi/lo fragment-major bf16 codebook ----
// unit u = cs*2+hh, c = (u>>1)*16 + (u&1)*8 + j
// cbF layout: [hi: (u*512+k)*16B for 64KB][lo: same, +64KB]
__global__ void __launch_bounds__(512)
vq_prep(const float* __restrict__ cb, float* __restrict__ esq, char* __restrict__ cbF) {
    __shared__ float tile[64 * 65];
    const int tid = threadIdx.x;
    const int k0  = blockIdx.x * 64;
    #pragma unroll
    for (int i = tid; i < 4096; i += 512)
        tile[(i >> 6) * 65 + (i & 63)] = cb[k0 * 64 + i];
    __syncthreads();
    const int u  = tid >> 6;
    const int kl = tid & 63;
    const float* row = tile + kl * 65;
    const int cbase = (u >> 1) * 16 + (u & 1) * 8;
    bf16x8 h8, l8;
    #pragma unroll
    for (int j = 0; j < 8; ++j) {
        float e = row[cbase + j];
        unsigned short hb = f2bf(e);
        float lo = e - bf2f(hb);
        h8[j] = (short)hb;
        l8[j] = (short)f2bf(lo);
    }
    const size_t idx = (size_t)(u * 512 + k0 + kl) * 16;
    *(bf16x8*)(cbF + idx)         = h8;
    *(bf16x8*)(cbF + 65536 + idx) = l8;
    if (u == 0) {
        float s = 0.f;
        #pragma unroll
        for (int c = 0; c < 64; ++c) { float v = row[c]; s = fmaf(v, v, s); }
        esq[k0 + kl] = s;
    }
}

// top-2 update; kq ascending -> strict < keeps first (numpy argmin semantics)
__device__ __forceinline__ void upd(float s, int kq, float& b1, int& q1, float& b2, int& q2) {
    bool t1 = s < b1;
    bool t2 = s < b2;
    float nb2 = t1 ? b1 : (t2 ? s : b2);
    int   nq2 = t1 ? q1 : (t2 ? kq : q2);
    b2 = nb2; q2 = nq2;
    b1 = t1 ? s : b1;
    q1 = t1 ? kq : q1;
}

// exact fp32 re-decision between k1,k2 (R2/R9-proven ordering)
__device__ __forceinline__ int refine_pair(int k1, int k2, long gx,
        const float* __restrict__ x, const float* __restrict__ cbg,
        const float* esq) {
    const float4* e1 = (const float4*)(cbg + (k1 << 6));
    const float4* e2 = (const float4*)(cbg + (k2 << 6));
    float a0 = 0.f, a1 = 0.f, c0 = 0.f, c1 = 0.f;
    #pragma unroll 4
    for (int j = 0; j < 16; ++j) {
        float4 ea = e1[j], eb = e2[j];
        float x0 = x[gx + (long)(4 * j + 0) * 4096];
        float x1 = x[gx + (long)(4 * j + 1) * 4096];
        float x2 = x[gx + (long)(4 * j + 2) * 4096];
        float x3 = x[gx + (long)(4 * j + 3) * 4096];
        a0 = fmaf(x0, ea.x, a0); a1 = fmaf(x1, ea.y, a1);
        a0 = fmaf(x2, ea.z, a0); a1 = fmaf(x3, ea.w, a1);
        c0 = fmaf(x0, eb.x, c0); c1 = fmaf(x1, eb.y, c1);
        c0 = fmaf(x2, eb.z, c0); c1 = fmaf(x3, eb.w, c1);
    }
    float s1 = esq[k1] - 2.f * (a0 + a1);
    float s2 = esq[k2] - 2.f * (c0 + c1);
    return (s2 < s1 || (s2 == s1 && k2 < k1)) ? k2 : k1;
}

// LDS: cbhi 16384 fl (64KB) | esq 512 fl = 67,584 B -> 2 blocks/CU, 4 waves/SIMD
#define AM_LDS_FLOATS 16896

__global__ void __launch_bounds__(512, 2)
vq_argmin(const float* __restrict__ x, const float* __restrict__ cbg,
          const float* __restrict__ esqg, const char* __restrict__ cbF,
          unsigned short* __restrict__ bkg, float* __restrict__ zero528) {
    extern __shared__ float lds[];
    float* esq = lds + 16384;
    const bf16x8* chi   = (const bf16x8*)lds;
    const bf16x8* clo_g = (const bf16x8*)(cbF + 65536);   // lo stays in L2 (64KB hot)
    const int tid  = threadIdx.x;
    const int lane = tid & 63;
    const int wv   = tid >> 6;     // 0..7
    const int l31  = lane & 31;
    const int hh   = lane >> 5;

    // ---- stage hi-codebook (coalesced float4 copy) + esq ----
    {
        const float4* src = (const float4*)cbF;
        float4* dst = (float4*)lds;
        #pragma unroll
        for (int i = tid; i < 4096; i += 512) dst[i] = src[i];
        esq[tid] = esqg[tid];
    }
    // zero hsum(512)+acc_loss(16): all blocks write 0 -- race-safe
    zero528[tid] = 0.f;
    if (tid < 16) zero528[512 + tid] = 0.f;

    // ---- B build: 1 n-tile per wave (-2x, hi/lo via cvt_pk; R9-proven) ----
    const int nb = blockIdx.x * 256 + wv * 32;    // this wave's 32 n
    bf16x8 Bh[4], Bl[4];
    {
        const int n = nb + l31;
        const long gx = (long)(n >> 12) * 262144 + (long)((n >> 6) & 63) * 64 + (n & 63);
        #pragma unroll
        for (int cs = 0; cs < 4; ++cs) {
            float v[8];
            #pragma unroll
            for (int j = 0; j < 8; ++j)
                v[j] = -2.f * x[gx + (long)(cs * 16 + hh * 8 + j) * 4096];
            union { unsigned u[4]; bf16x8 v8; } uh, ul;
            #pragma unroll
            for (int p = 0; p < 4; ++p) {
                unsigned hp, lp;
                asm("v_cvt_pk_bf16_f32 %0, %1, %2" : "=v"(hp) : "v"(v[2*p]), "v"(v[2*p+1]));
                float r0 = v[2*p]     - __uint_as_float(hp << 16);
                float r1 = v[2*p + 1] - __uint_as_float(hp & 0xFFFF0000u);
                asm("v_cvt_pk_bf16_f32 %0, %1, %2" : "=v"(lp) : "v"(r0), "v"(r1));
                uh.u[p] = hp; ul.u[p] = lp;
            }
            Bh[cs] = uh.v8; Bl[cs] = ul.v8;
        }
    }
    __syncthreads();

    // ---- K loop: 16 tiles x 32 codes; Ah from LDS, Al from L2 (ping-pong) ----
    float b1 = 3.4e38f, b2 = 3.4e38f;
    int   q1 = 0, q2 = 0;
    bf16x8 Xl[4], Yl[4];

#define LOADAL(Al, kt) { _Pragma("unroll") for (int cs = 0; cs < 4; ++cs) { \
        Al[cs] = clo_g[(cs * 2 + hh) * 512 + (kt) * 32 + l31]; } }

#define STEP(Al, kt) { \
        bf16x8 Ah[4]; \
        _Pragma("unroll") for (int cs = 0; cs < 4; ++cs) \
            Ah[cs] = chi[(cs * 2 + hh) * 512 + (kt) * 32 + l31]; \
        f32x16 acc; \
        _Pragma("unroll") for (int g = 0; g < 4; ++g) { \
            float4 e4 = *(const float4*)(esq + (kt) * 32 + 8 * g + 4 * hh); \
            acc[4*g] = e4.x; acc[4*g+1] = e4.y; acc[4*g+2] = e4.z; acc[4*g+3] = e4.w; } \
        _Pragma("unroll") for (int cs = 0; cs < 4; ++cs) { \
            acc = MFMA32(Ah[cs], Bh[cs], acc, 0, 0, 0); \
            acc = MFMA32(Al[cs], Bh[cs], acc, 0, 0, 0); \
            acc = MFMA32(Ah[cs], Bl[cs], acc, 0, 0, 0); } \
        _Pragma("unroll") for (int e = 0; e < 16; ++e) { \
            int kq = (kt) * 32 + (e & 3) + 8 * (e >> 2); \
            upd(acc[e], kq, b1, q1, b2, q2); } }

    LOADAL(Xl, 0)
    #pragma unroll 1
    for (int ktp = 0; ktp < 16; ktp += 2) {
        LOADAL(Yl, ktp + 1)
        STEP(Xl, ktp)
        if (ktp + 2 < 16) LOADAL(Xl, ktp + 2)
        STEP(Yl, ktp + 1)
    }

    // ---- merge hh halves (true k = kq + 4*hh) + in-kernel refine + final bkg ----
    {
        float mb1 = b1, mb2 = b2;
        int   mk1 = q1 + 4 * hh, mk2 = q2 + 4 * hh;
        float ob1 = __shfl_xor(mb1, 32, 64); int ok1 = __shfl_xor(mk1, 32, 64);
        float ob2 = __shfl_xor(mb2, 32, 64); int ok2 = __shfl_xor(mk2, 32, 64);
        bool t = (ob1 < mb1) || (ob1 == mb1 && ok1 < mk1);
        float w1 = t ? ob1 : mb1;  int wk1 = t ? ok1 : mk1;
        float l1 = t ? mb1 : ob1;  int lk1 = t ? mk1 : ok1;
        float w2c = t ? ob2 : mb2; int wk2c = t ? ok2 : mk2;
        bool t2 = (w2c < l1) || (w2c == l1 && wk2c < lk1);
        float w2 = t2 ? w2c : l1;  int wk2 = t2 ? wk2c : lk1;
        if (hh == 0) {
            int kk = wk1;
            if (wk2 != wk1 && (w2 - w1 < 2e-3f)) {
                const int n = nb + l31;
                const long gx = (long)(n >> 12) * 262144
                              + (long)((n >> 6) & 63) * 64 + (n & 63);
                kk = refine_pair(wk1, wk2, gx, x, cbg, esq);
            }
            bkg[nb + l31] = (unsigned short)kk;
        }
    }
#undef LOADAL
#undef STEP
}

// ---- fused consumers of bkg: blocks 0-255 out/loss/hist, 256-511 segsum GEMM ----
// dynamic LDS: 33536 ushort = 67,072 B (segsum: xb 64*516 + kb 512; out: 520 fl)
#define FUSED_LDS_BYTES (33536 * 2)

__global__ void __launch_bounds__(512)
vq_fused(const float* __restrict__ x, const float* __restrict__ cbg,
         const unsigned short* __restrict__ bkg, float* __restrict__ out,
         float* __restrict__ hsum, float* __restrict__ acc_loss,
         float* __restrict__ slabs) {
    extern __shared__ unsigned short sm16[];
    const int tid = threadIdx.x;
    if (blockIdx.x < 256) {
        // ---- out (= q, == x+(q-x) to 1 ulp, R5-proven) + loss + counts ----
        float* hist = (float*)sm16;          // 512 floats
        float* lred = (float*)sm16 + 512;    // 8 floats
        hist[tid] = 0.f;
        __syncthreads();
        const int n  = blockIdx.x * 512 + tid;
        const long gx = (long)(n >> 12) * 262144 + (long)((n >> 6) & 63) * 64 + (n & 63);
        const int k1 = bkg[n];
        atomicAdd(&hist[k1], 1.0f);
        const float4* q4 = (const float4*)(cbg + (k1 << 6));
        float lsum = 0.f;
        #pragma unroll
        for (int j = 0; j < 16; ++j) {
            float4 q = q4[j];
            const float qv[4] = {q.x, q.y, q.z, q.w};
            #pragma unroll
            for (int r = 0; r < 4; ++r) {
                const int c = 4 * j + r;
                float xc = x[gx + (long)c * 4096];
                out[gx + (long)c * 4096] = qv[r];
                float d = xc - qv[r];
                lsum = fmaf(d, d, lsum);
            }
        }
        #pragma unroll
        for (int o = 32; o > 0; o >>= 1) lsum += __shfl_down(lsum, o, 64);
        if ((tid & 63) == 0) lred[tid >> 6] = lsum;
        __syncthreads();
        if (tid == 0) {
            float l = ((lred[0] + lred[1]) + (lred[2] + lred[3]))
                    + ((lred[4] + lred[5]) + (lred[6] + lred[7]));
            atomicAdd(acc_loss, l);
        }
        { float v = hist[tid]; if (v != 0.f) atomicAdd(&hsum[tid], v); }
    } else {
        // ---- segment sum as onehot MFMA GEMM, LDS-staged x-tile (R9 math) ----
        unsigned short* xb = sm16;           // [64][516] bf16, 516-pad
        unsigned short* kb = sm16 + 33024;   // 512 indices
        const int lane = tid & 63;
        const int w    = tid >> 6;
        const int l31  = lane & 31;
        const int hh   = lane >> 5;
        const int bix  = blockIdx.x - 256;
        const int n0   = bix * 512;
        const float* xpl = x + (long)(n0 >> 12) * 262144 + (n0 & 4095);

        kb[tid] = bkg[n0 + tid];
        #pragma unroll
        for (int i = 0; i < 16; ++i) {
            const int f  = tid + i * 512;        // 0..8191 float4s
            const int c  = f >> 7;
            const int n4 = (f & 127) << 2;
            float4 v = *(const float4*)(xpl + (long)c * 4096 + n4);
            ushort4 o;
            o.x = f2bf(v.x); o.y = f2bf(v.y); o.z = f2bf(v.z); o.w = f2bf(v.w);
            *(ushort4*)(xb + c * 516 + n4) = o;
        }
        __syncthreads();

        const int t0 = w * 32 + l31;
        const int t1 = (w + 8) * 32 + l31;
        f32x16 aA0 = {}, aA1 = {}, aB0 = {}, aB1 = {};

        #pragma unroll 1
        for (int b16 = 0; b16 < 32; ++b16) {
            const int nofs = b16 * 16 + hh * 8;
            ushort4 p0a = *(const ushort4*)(xb + l31 * 516 + nofs);
            ushort4 p0b = *(const ushort4*)(xb + l31 * 516 + nofs + 4);
            ushort4 p1a = *(const ushort4*)(xb + (32 + l31) * 516 + nofs);
            ushort4 p1b = *(const ushort4*)(xb + (32 + l31) * 516 + nofs + 4);
            bf16x8 Bf0, Bf1;
            Bf0[0] = (short)p0a.x; Bf0[1] = (short)p0a.y;
            Bf0[2] = (short)p0a.z; Bf0[3] = (short)p0a.w;
            Bf0[4] = (short)p0b.x; Bf0[5] = (short)p0b.y;
            Bf0[6] = (short)p0b.z; Bf0[7] = (short)p0b.w;
            Bf1[0] = (short)p1a.x; Bf1[1] = (short)p1a.y;
            Bf1[2] = (short)p1a.z; Bf1[3] = (short)p1a.w;
            Bf1[4] = (short)p1b.x; Bf1[5] = (short)p1b.y;
            Bf1[6] = (short)p1b.z; Bf1[7] = (short)p1b.w;
            ushort4 k4a = *(const ushort4*)(kb + nofs);
            ushort4 k4b = *(const ushort4*)(kb + nofs + 4);
            const int kk[8] = {k4a.x, k4a.y, k4a.z, k4a.w,
                               k4b.x, k4b.y, k4b.z, k4b.w};
            bf16x8 A0, A1;
            #pragma unroll
            for (int j = 0; j < 8; ++j) {
                A0[j] = (kk[j] == t0) ? (short)0x3F80 : (short)0;
                A1[j] = (kk[j] == t1) ? (short)0x3F80 : (short)0;
            }
            aA0 = MFMA32(A0, Bf0, aA0, 0, 0, 0);
            aA1 = MFMA32(A0, Bf1, aA1, 0, 0, 0);
            aB0 = MFMA32(A1, Bf0, aB0, 0, 0, 0);
            aB1 = MFMA32(A1, Bf1, aB1, 0, 0, 0);
        }
        float* slab = slabs + (long)bix * 32768;
        #pragma unroll
        for (int e = 0; e < 16; ++e) {
            const int row = (e & 3) + 8 * (e >> 2) + 4 * hh;
            slab[(w * 32 + row) * 64 + l31]            = aA0[e];
            slab[(w * 32 + row) * 64 + 32 + l31]       = aA1[e];
            slab[((w + 8) * 32 + row) * 64 + l31]      = aB0[e];
            slab[((w + 8) * 32 + row) * 64 + 32 + l31] = aB1[e];
        }
    }
}

// ---- final: scalars (block 0) + codebook; smoothed recomputed per block ----
__global__ void __launch_bounds__(512)
vq_final(const float* __restrict__ slabs, const float* __restrict__ hsum,
         const float* __restrict__ acc_loss, const float* __restrict__ ema_cs,
         const float* __restrict__ ema_w, float* __restrict__ out_scalars,
         float* __restrict__ out_cb) {
    __shared__ float sm[512];
    __shared__ float s_red[17];
    const int tid = threadIdx.x;           // tid == code k
    float cnt = hsum[tid];
    float ncs = 0.99f * ema_cs[tid] + 0.01f * cnt;
    float v1 = ncs;
    float v2 = (cnt > 0.f) ? 1.f : 0.f;
    #pragma unroll
    for (int o = 32; o > 0; o >>= 1) {
        v1 += __shfl_down(v1, o, 64);
        v2 += __shfl_down(v2, o, 64);
    }
    const int wv = tid >> 6;
    if ((tid & 63) == 0) { s_red[wv] = v1; s_red[wv + 8] = v2; }
    __syncthreads();
    if (tid == 0) {
        float nn = 0.f, uq = 0.f;
        #pragma unroll
        for (int i = 0; i < 8; ++i) { nn += s_red[i]; uq += s_red[i + 8]; }
        s_red[16] = nn;
        if (blockIdx.x == 0) {
            out_scalars[0] = acc_loss[0] / 8388608.f;
            out_scalars[1] = uq;
        }
    }
    __syncthreads();
    float nn = s_red[16];
    sm[tid] = (ncs + 1e-5f) / (nn + 512.f * 1e-5f) * nn;
    __syncthreads();
    const int e = blockIdx.x * 512 + tid;  // e = k*64 + c
    float s = 0.f;
    #pragma unroll 8
    for (int b = 0; b < 256; ++b) s += slabs[(long)b * 32768 + e];
    float nw = 0.99f * ema_w[e] + 0.01f * s;
    out_cb[e] = nw / sm[e >> 6];
}

extern "C" void kernel_launch(void* const* d_in, const int* in_sizes, int n_in,
                              void* d_out, int out_size, void* d_ws, size_t ws_size,
                              hipStream_t stream) {
    const float* x      = (const float*)d_in[0];
    const float* cb     = (const float*)d_in[1];
    const float* ema_cs = (const float*)d_in[2];
    const float* ema_w  = (const float*)d_in[3];

    float* out     = (float*)d_out;
    float* scalars = out + 8388608;
    float* out_cb  = out + 8388610;
    float* ws      = (float*)d_ws;

    // ws layout (floats):
    float* slabs    = ws;                               // 256*32768 = 8,388,608 (32MB)
    float* hsum     = slabs + 8388608;                  // 512
    float* acc_loss = hsum + 512;                       // 16
    float* esq      = acc_loss + 16;                    // 512
    char*  cbF      = (char*)(esq + 512);               // 131072 B
    unsigned short* bkg = (unsigned short*)(cbF + 131072);   // 131072 u16
    // total ~34.1 MB (R4 proved >= 34.6 MB available)

    vq_prep<<<8, 512, 0, stream>>>(cb, esq, cbF);
    vq_argmin<<<512, 512, AM_LDS_FLOATS * sizeof(float), stream>>>(x, cb, esq, cbF, bkg, hsum);
    vq_fused<<<512, 512, FUSED_LDS_BYTES, stream>>>(x, cb, bkg, out, hsum, acc_loss, slabs);
    vq_final<<<64, 512, 0, stream>>>(slabs, hsum, acc_loss, ema_cs, ema_w, scalars, out_cb);
}